// Round 4
// baseline (1244.763 us; speedup 1.0000x reference)
//
#include <hip/hip_runtime.h>
#include <stdint.h>

typedef __attribute__((ext_vector_type(8))) short s16x8;
typedef __attribute__((ext_vector_type(4))) float f32x4;
typedef unsigned short u16;

#define DEV static __device__ __forceinline__

DEV f32x4 mfma16(s16x8 a, s16x8 b, f32x4 c) {
    return __builtin_amdgcn_mfma_f32_16x16x32_bf16(a, b, c, 0, 0, 0);
}

DEV void gld16(const void* g, void* l) {
    __builtin_amdgcn_global_load_lds(
        (const __attribute__((address_space(1))) void*)g,
        (__attribute__((address_space(3))) void*)l, 16, 0, 0);
}

DEV u16 f2bf(float x) {
    union { float f; unsigned u; } v; v.f = x;
    unsigned r = v.u + 0x7FFFu + ((v.u >> 16) & 1u);
    return (u16)(r >> 16);
}
DEV float bf2f(u16 h) { return __uint_as_float(((unsigned)h) << 16); }

#define SBAR() do { __builtin_amdgcn_sched_barrier(0); __builtin_amdgcn_s_barrier(); __builtin_amdgcn_sched_barrier(0); } while (0)
#define LGKM0() do { asm volatile("s_waitcnt lgkmcnt(0)" ::: "memory"); __builtin_amdgcn_sched_barrier(0); } while (0)

// ---------------- weight / input conversion ----------------
struct WPtrs { const float* p[16]; };

__global__ void k_conv_w(WPtrs wp, u16* wd, u16* wq) {
    int t = blockIdx.x * 256 + threadIdx.x;
    int mat = t >> 14;
    int e = (t & 16383) << 2;
    const float* s = wp.p[mat] + e;
    u16* d = (mat < 8 ? wd + mat * 65536 : wq + (mat - 8) * 65536) + e;
    float4 v = *(const float4*)s;
    d[0] = f2bf(v.x); d[1] = f2bf(v.y); d[2] = f2bf(v.z); d[3] = f2bf(v.w);
}

__global__ void k_conv_x(const float* dn, const float* qn, u16* xd, u16* xq) {
    int t = blockIdx.x * 256 + threadIdx.x;
    int h = t >> 19;
    int e = (t & 524287) << 2;
    const float* s = (h ? qn : dn) + e;
    u16* d = (h ? xq : xd) + e;
    float4 v = *(const float4*)s;
    d[0] = f2bf(v.x); d[1] = f2bf(v.y); d[2] = f2bf(v.z); d[3] = f2bf(v.w);
}

// ---------------- projection GEMM: out = X @ W^T ----------------
__global__ __launch_bounds__(256, 1) void k_proj(const u16* xd, const u16* xq,
        const u16* wdm, const u16* wqm, u16* tokd, u16* tokq, u16* vtd, u16* vtq) {
    __shared__ __align__(16) char smem[16384];
    char* As = smem; char* Bs = smem + 8192;
    const int lane = threadIdx.x & 63, wid = threadIdx.x >> 6;
    const int z = blockIdx.z, grp = z >> 3, w = z & 7;
    const u16* X = grp ? xq : xd;
    const u16* W = (grp ? wqm : wdm) + w * 65536;
    const int m0 = blockIdx.x * 128, n0 = blockIdx.y * 128;
    const int wr = wid >> 1, wc = wid & 1;
    const int rl = lane & 15, g = lane >> 4;
    const f32x4 fz = {0.f, 0.f, 0.f, 0.f};
    f32x4 acc[4][4];
#pragma unroll
    for (int i = 0; i < 4; ++i)
#pragma unroll
        for (int j = 0; j < 4; ++j) acc[i][j] = fz;

    for (int kt = 0; kt < 8; ++kt) {
#pragma unroll
        for (int t = 0; t < 2; ++t) {
            int iid = wid * 2 + t;
            int ldso = iid * 1024 + lane * 16;
            int row = ldso >> 6, inrow = ldso & 63;
            int src = inrow ^ ((row & 3) << 4);
            gld16((const char*)X + ((size_t)(m0 + row) * 512 + kt * 64 + src), As + iid * 1024);
            gld16((const char*)W + ((size_t)(n0 + row) * 512 + kt * 64 + src), Bs + iid * 1024);
        }
        __syncthreads();
        s16x8 av[4], bv[4];
#pragma unroll
        for (int rf = 0; rf < 4; ++rf) {
            int row = wr * 64 + rf * 16 + rl;
            av[rf] = *(const s16x8*)(As + row * 64 + ((g * 16) ^ ((row & 3) << 4)));
        }
#pragma unroll
        for (int cf = 0; cf < 4; ++cf) {
            int row = wc * 64 + cf * 16 + rl;
            bv[cf] = *(const s16x8*)(Bs + row * 64 + ((g * 16) ^ ((row & 3) << 4)));
        }
#pragma unroll
        for (int rf = 0; rf < 4; ++rf)
#pragma unroll
            for (int cf = 0; cf < 4; ++cf)
                acc[rf][cf] = mfma16(av[rf], bv[cf], acc[rf][cf]);
        __syncthreads();
    }
    if (w < 4) {
        u16* out = (grp ? tokq : tokd) + (size_t)w * 2097152;
#pragma unroll
        for (int rf = 0; rf < 4; ++rf)
#pragma unroll
            for (int cf = 0; cf < 4; ++cf) {
                int n = n0 + wc * 64 + cf * 16 + rl;
                int m = m0 + wr * 64 + rf * 16 + g * 4;
#pragma unroll
                for (int r = 0; r < 4; ++r)
                    out[(size_t)(m + r) * 256 + n] = f2bf(acc[rf][cf][r]);
            }
    } else {
        u16* out = (grp ? vtq : vtd) + (size_t)(w - 4) * 2097152;
#pragma unroll
        for (int rf = 0; rf < 4; ++rf)
#pragma unroll
            for (int cf = 0; cf < 4; ++cf) {
                int n = n0 + wc * 64 + cf * 16 + rl;
                int m = m0 + wr * 64 + rf * 16 + g * 4;
                int b = m >> 10, tok = m & 1023;
                unsigned lo = (unsigned)f2bf(acc[rf][cf][0]) | ((unsigned)f2bf(acc[rf][cf][1]) << 16);
                unsigned hi = (unsigned)f2bf(acc[rf][cf][2]) | ((unsigned)f2bf(acc[rf][cf][3]) << 16);
                uint2 u; u.x = lo; u.y = hi;
                *(uint2*)(out + ((size_t)(b * 256 + n)) * 1024 + tok) = u;
            }
    }
}

// ---------------- fused masked attention (one quadrant per z) ----------------
struct PhaseCfg {
    const u16* Q; const u16* K; const u16* Vl; const u16* Vr;
    const int* rm; const int* cm;
    int roff, coff; float scale;
    float* po; float* nbOut;
};

// BM=32, j-tile=32, 4 waves in 2x2 (ws=row strip, wc=col half).
// Single K buffer (M barrier = WAR fence); V direct from global (channel-major);
// P single-buffered. Writes normalized quadrant partial + nb rowsum.
// LDS 22400B: Ks@0 (16384); Pl@16384 (2560); Pr@18944 (2560);
//   mxS@21504 (256); rsS@21760 (128); dpS@21888 (256); nbpS@22144 (256)
__global__ __launch_bounds__(256, 4) void k_attn(PhaseCfg c0, PhaseCfg c1,
        PhaseCfg c2, PhaseCfg c3, const int* ner, const int* graph) {
    const int z = blockIdx.z;
    const PhaseCfg c = z == 0 ? c0 : z == 1 ? c1 : z == 2 ? c2 : c3;
    const int b = blockIdx.y;
    const int i0 = blockIdx.x * 32;
    const int lane = threadIdx.x & 63, w = threadIdx.x >> 6;
    const int ws = w >> 1, wc = w & 1;
    const int rl = lane & 15, g = lane >> 4;

    __shared__ __align__(16) char smem[22400];
    u16* Pls = (u16*)(smem + 16384);
    u16* Prs = (u16*)(smem + 18944);
    float* mxS  = (float*)(smem + 21504);
    float* rsS  = (float*)(smem + 21760);
    float* dpS  = (float*)(smem + 21888);
    float* nbpS = (float*)(smem + 22144);

    // Q fragments: rows i0+ws*16+rl, k = kf*32 + g*8 .. +8 (bf16 always)
    s16x8 qf[8];
    {
        const u16* Qb = c.Q + (size_t)(b * 1024 + i0 + ws * 16 + rl) * 256 + g * 8;
#pragma unroll
        for (int kf = 0; kf < 8; ++kf) qf[kf] = *(const s16x8*)(Qb + kf * 32);
    }
    const int iqb = i0 + ws * 16 + g * 4;
    int rmv[4];
#pragma unroll
    for (int r = 0; r < 4; ++r)
        rmv[r] = c.rm[b * 1024 + iqb + r] != 0;

    const size_t mb0 = ((size_t)(b * 2048 + c.roff + iqb)) * 2048 + c.coff + wc * 16;
    const int* nrb = ner + mb0;
    const int* grb = graph + mb0;
    const int* cmp = c.cm + b * 1024 + wc * 16;

    const f32x4 fz = {0.f,0.f,0.f,0.f};
    f32x4 accl[2][4], accr[2][4];
#pragma unroll
    for (int i = 0; i < 2; ++i)
#pragma unroll
        for (int j = 0; j < 4; ++j) { accl[i][j] = fz; accr[i][j] = fz; }
    float mrow[4] = {-1e30f,-1e30f,-1e30f,-1e30f};
    float dden[4] = {0.f,0.f,0.f,0.f};
    float nbc[4]  = {0.f,0.f,0.f,0.f};

    const char* Kg  = (const char*)c.K  + (size_t)b * 524288;
    const char* Vlg = (const char*)c.Vl + (size_t)b * 524288;
    const char* Vrg = (const char*)c.Vr + (size_t)b * 524288;

    auto STAGE_K = [&](int j0) {
#pragma unroll
        for (int t = 0; t < 4; ++t) {
            int iid = w * 4 + t;
            int ldso = iid * 1024 + lane * 16;
            int row = ldso >> 9, inrow = ldso & 511;
            int src = inrow ^ ((row & 7) << 4);
            gld16(Kg + ((size_t)(j0 + row) * 512 + src), smem + iid * 1024);
        }
    };

    int mn[4], mg[4], mc;
    auto MLOAD = [&](int j0) {
#pragma unroll
        for (int r = 0; r < 4; ++r) {
            mn[r] = nrb[r * 2048 + j0 + rl];
            mg[r] = grb[r * 2048 + j0 + rl];
        }
        mc = cmp[j0 + rl];
    };

    STAGE_K(0);
    MLOAD(0);

#pragma unroll 1
    for (int jt = 0; jt < 32; ++jt) {
        const int j0 = jt * 32;

        // V fragments direct from global (channel-major, 16B coalesced)
        s16x8 vl[4], vr[4];
#pragma unroll
        for (int cf = 0; cf < 4; ++cf) {
            size_t off = (size_t)(w * 64 + cf * 16 + rl) * 2048 + (size_t)(j0 + g * 8) * 2;
            vl[cf] = *(const s16x8*)(Vlg + off);
            vr[cf] = *(const s16x8*)(Vrg + off);
        }
        // queue: STAGE_K(jt)=4 (oldest), MLOAD(jt)=9, V=8 -> drain K only
        asm volatile("s_waitcnt vmcnt(17)" ::: "memory");
        SBAR();   // (A) K tile visible

        // S = Q K^T : wave's 16 rows x 16 cols (cols wc*16..+16)
        f32x4 s0 = fz;
#pragma unroll
        for (int kk = 0; kk < 8; ++kk) {
            int jr = wc * 16 + rl;
            s16x8 b0 = *(const s16x8*)(smem + jr * 512 + ((kk * 64 + g * 16) ^ ((jr & 7) << 4)));
            s0 = mfma16(qf[kk], b0, s0);
        }

        const int jq = j0 + wc * 16 + rl;
        const int cmv = mc != 0;
        float sv[4]; int lm[4], rm2[4];
#pragma unroll
        for (int r = 0; r < 4; ++r) {
            int nv = mn[r] != 0, gv = mg[r] != 0;
            int v0 = rmv[r] & cmv & nv;
            int e0 = v0 & (int)((c.roff + iqb + r) != (c.coff + jq));
            sv[r] = v0 ? s0[r] * c.scale : -1e30f;
            lm[r] = e0 & gv;  rm2[r] = e0 & (gv ^ 1);
            nbc[r] += (float)e0;
        }
        float tl[4];
#pragma unroll
        for (int r = 0; r < 4; ++r) {
            float t = sv[r];
            t = fmaxf(t, __shfl_xor(t, 1));
            t = fmaxf(t, __shfl_xor(t, 2));
            t = fmaxf(t, __shfl_xor(t, 4));
            t = fmaxf(t, __shfl_xor(t, 8));
            tl[r] = t;
        }
        if (rl == 0) {
            f32x4 tv = {tl[0], tl[1], tl[2], tl[3]};
            *(f32x4*)(mxS + wc * 32 + ws * 16 + g * 4) = tv;
        }
        LGKM0();
        SBAR();   // (M) maxima visible; K reads all done -> WAR fence

        if (jt < 31) STAGE_K(j0 + 32);   // single buffer, safe after M

        f32x4 mo = *(const f32x4*)(mxS + (wc ^ 1) * 32 + ws * 16 + g * 4);
        float rsv[4];
#pragma unroll
        for (int r = 0; r < 4; ++r) {
            float mn2 = fmaxf(mrow[r], fmaxf(tl[r], mo[r]));
            rsv[r] = __expf(mrow[r] - mn2);
            mrow[r] = mn2;
            float e0 = __expf(sv[r] - mn2);
            dden[r] = dden[r] * rsv[r] + e0;
            int prow = ws * 16 + g * 4 + r;
            Pls[prow * 40 + wc * 16 + rl] = lm[r]  ? f2bf(e0) : (u16)0;
            Prs[prow * 40 + wc * 16 + rl] = rm2[r] ? f2bf(e0) : (u16)0;
        }
        if (rl == 0 && wc == 0) {
            f32x4 rv = {rsv[0], rsv[1], rsv[2], rsv[3]};
            *(f32x4*)(rsS + ws * 16 + g * 4) = rv;
        }
        LGKM0();
        SBAR();   // (B) P + rescale visible

        if (jt < 31) MLOAD(j0 + 32);

        // PV: wave's 64-channel slice over all 32 rows
        f32x4 rs4[2];
#pragma unroll
        for (int rf = 0; rf < 2; ++rf) rs4[rf] = *(const f32x4*)(rsS + rf * 16 + g * 4);
#pragma unroll
        for (int rf = 0; rf < 2; ++rf)
#pragma unroll
            for (int cf = 0; cf < 4; ++cf) { accl[rf][cf] *= rs4[rf]; accr[rf][cf] *= rs4[rf]; }
        s16x8 pa[2], pb[2];
#pragma unroll
        for (int rf = 0; rf < 2; ++rf) {
            pa[rf] = *(const s16x8*)((char*)Pls + (rf * 16 + rl) * 80 + g * 16);
            pb[rf] = *(const s16x8*)((char*)Prs + (rf * 16 + rl) * 80 + g * 16);
        }
#pragma unroll
        for (int rf = 0; rf < 2; ++rf)
#pragma unroll
            for (int cf = 0; cf < 4; ++cf) {
                accl[rf][cf] = mfma16(pa[rf], vl[cf], accl[rf][cf]);
                accr[rf][cf] = mfma16(pb[rf], vr[cf], accr[rf][cf]);
            }
    }

    // reduce row stats over rl, publish per col-half
#pragma unroll
    for (int r = 0; r < 4; ++r) {
        float d = dden[r];
        d += __shfl_xor(d, 1); d += __shfl_xor(d, 2); d += __shfl_xor(d, 4); d += __shfl_xor(d, 8);
        dden[r] = d;
        float nn = nbc[r];
        nn += __shfl_xor(nn, 1); nn += __shfl_xor(nn, 2); nn += __shfl_xor(nn, 4); nn += __shfl_xor(nn, 8);
        nbc[r] = nn;
    }
    if (rl == 0) {
        f32x4 dv = {dden[0], dden[1], dden[2], dden[3]};
        *(f32x4*)(dpS + wc * 32 + ws * 16 + g * 4) = dv;
        f32x4 nv = {nbc[0], nbc[1], nbc[2], nbc[3]};
        *(f32x4*)(nbpS + wc * 32 + ws * 16 + g * 4) = nv;
    }
    __syncthreads();

    if (rl == 0 && wc == 0) {
        f32x4 n0 = *(const f32x4*)(nbpS + ws * 16 + g * 4);
        f32x4 n1 = *(const f32x4*)(nbpS + 32 + ws * 16 + g * 4);
        f32x4 nt = n0 + n1;
        *(f32x4*)(c.nbOut + b * 1024 + i0 + ws * 16 + g * 4) = nt;
    }
#pragma unroll
    for (int rf = 0; rf < 2; ++rf) {
        f32x4 d0 = *(const f32x4*)(dpS + rf * 16 + g * 4);
        f32x4 d1 = *(const f32x4*)(dpS + 32 + rf * 16 + g * 4);
        f32x4 dt = d0 + d1;
#pragma unroll
        for (int cf = 0; cf < 4; ++cf) {
            int col = w * 64 + cf * 16 + rl;
#pragma unroll
            for (int r = 0; r < 4; ++r) {
                int row = i0 + rf * 16 + g * 4 + r;
                size_t oi = (size_t)(b * 1024 + row) * 256 + col;
                float inv = dt[r] > 0.f ? 1.f / dt[r] : 0.f;
                c.po[oi] = (accl[rf][cf][r] + accr[rf][cf][r]) * inv;
            }
        }
    }
}

// ---------------- combine: out = relu(self + bias + (pA+pB)/max(nbA+nbB,1)) ----------------
struct FinCfg {
    const float* pA; const float* pB; const float* nbA; const float* nbB;
    const u16* self; float* out;
};

__global__ __launch_bounds__(256) void k_fin(FinCfg f0, FinCfg f1, const float* bias) {
    const FinCfg f = blockIdx.y ? f1 : f0;
    int row = blockIdx.x * 4 + (threadIdx.x >> 6);   // 0..8191 (b*1024+i)
    int ch = (threadIdx.x & 63) * 4;
    size_t oi = (size_t)row * 256 + ch;
    float inv = 1.f / fmaxf(f.nbA[row] + f.nbB[row], 1.f);
    f32x4 a = *(const f32x4*)(f.pA + oi);
    f32x4 p = *(const f32x4*)(f.pB + oi);
    f32x4 bi = *(const f32x4*)(bias + ch);
    uint2 sv = *(const uint2*)(f.self + oi);
    float s[4] = { bf2f((u16)(sv.x & 0xffff)), bf2f((u16)(sv.x >> 16)),
                   bf2f((u16)(sv.y & 0xffff)), bf2f((u16)(sv.y >> 16)) };
    f32x4 o;
#pragma unroll
    for (int k = 0; k < 4; ++k)
        o[k] = fmaxf(s[k] + bi[k] + (a[k] + p[k]) * inv, 0.f);
    *(f32x4*)(f.out + oi) = o;
}

// ---------------- host ----------------
extern "C" void kernel_launch(void* const* d_in, const int* in_sizes, int n_in,
                              void* d_out, int out_size, void* d_ws, size_t ws_size,
                              hipStream_t stream) {
    (void)in_sizes; (void)n_in; (void)out_size; (void)ws_size;
    const float* d_node = (const float*)d_in[0];
    const float* q_node = (const float*)d_in[1];
    const float* b_self = (const float*)d_in[9];
    const int* dm = (const int*)d_in[18];
    const int* qm = (const int*)d_in[19];
    const int* ner = (const int*)d_in[20];
    const int* graph = (const int*)d_in[21];

    char* ws = (char*)d_ws;
    const size_t MB = 1024 * 1024;
    u16* xd   = (u16*)(ws + 0 * MB);
    u16* xq   = (u16*)(ws + 4 * MB);
    u16* wdm  = (u16*)(ws + 8 * MB);
    u16* wqm  = (u16*)(ws + 9 * MB);
    u16* tokd = (u16*)(ws + 10 * MB);     // [Qd, Kd, Kqd, SelfD]
    u16* tokq = (u16*)(ws + 26 * MB);     // [Qq, Kq, Kdq, SelfQ]
    u16* vtd  = (u16*)(ws + 42 * MB);     // [ddl, ddr, qdl, qdr] channel-major
    u16* vtq  = (u16*)(ws + 58 * MB);     // [qql, qqr, dql, dqr]
    float* nbdd = (float*)(ws + 74 * MB);
    float* nbqq = (float*)(ws + 74 * MB + 32768);
    float* nbdq = (float*)(ws + 74 * MB + 65536);
    float* nbqd = (float*)(ws + 74 * MB + 98304);
    float* Pdq  = (float*)(ws + 75 * MB);     // 8 MB
    float* Pqd  = (float*)(ws + 83 * MB);     // 8 MB

    float* outd = (float*)d_out;              // also holds Pdd partial
    float* outq = outd + 2097152;             // also holds Pqq partial

    WPtrs wp;
    wp.p[0]  = (const float*)d_in[2];   // W_dq_query -> Qd
    wp.p[1]  = (const float*)d_in[3];   // W_dk_key   -> Kd
    wp.p[2]  = (const float*)d_in[7];   // W_qd_fc    -> Kqd
    wp.p[3]  = (const float*)d_in[8];   // W_self     -> SelfD
    wp.p[4]  = (const float*)d_in[10];  // W_dd_l
    wp.p[5]  = (const float*)d_in[14];  // W_dd_r
    wp.p[6]  = (const float*)d_in[13];  // W_qd_l
    wp.p[7]  = (const float*)d_in[17];  // W_qd_r
    wp.p[8]  = (const float*)d_in[4];   // W_qq_query -> Qq
    wp.p[9]  = (const float*)d_in[5];   // W_qk_key   -> Kq
    wp.p[10] = (const float*)d_in[6];   // W_dq_fc    -> Kdq
    wp.p[11] = (const float*)d_in[8];   // W_self     -> SelfQ
    wp.p[12] = (const float*)d_in[11];  // W_qq_l
    wp.p[13] = (const float*)d_in[15];  // W_qq_r
    wp.p[14] = (const float*)d_in[12];  // W_dq_l
    wp.p[15] = (const float*)d_in[16];  // W_dq_r

    k_conv_w<<<1024, 256, 0, stream>>>(wp, wdm, wqm);
    k_conv_x<<<4096, 256, 0, stream>>>(d_node, q_node, xd, xq);
    k_proj<<<dim3(64, 2, 16), 256, 0, stream>>>(xd, xq, wdm, wqm, tokd, tokq, vtd, vtq);

    const size_t M2 = 2097152;
    PhaseCfg dd = { tokd,          tokd + M2,     vtd,          vtd + M2,
                    dm, dm, 0, 0, 0.0625f, outd, nbdd };
    PhaseCfg qq = { tokq,          tokq + M2,     vtq,          vtq + M2,
                    qm, qm, 1024, 1024, 0.0625f, outq, nbqq };
    PhaseCfg dq = { xd,            tokq + 2 * M2, vtq + 2 * M2, vtq + 3 * M2,
                    dm, qm, 0, 1024, 1.0f, Pdq, nbdq };
    PhaseCfg qd = { xq,            tokd + 2 * M2, vtd + 2 * M2, vtd + 3 * M2,
                    qm, dm, 1024, 0, 1.0f, Pqd, nbqd };
    k_attn<<<dim3(32, 8, 4), 256, 0, stream>>>(dd, qq, dq, qd, ner, graph);

    FinCfg fd = { outd, Pdq, nbdd, nbdq, tokd + 3 * M2, outd };
    FinCfg fq = { outq, Pqd, nbqq, nbqd, tokq + 3 * M2, outq };
    k_fin<<<dim3(2048, 2), 256, 0, stream>>>(fd, fq, b_self);
}

// Round 5
// 1024.900 us; speedup vs baseline: 1.2145x; 1.2145x over previous
//
#include <hip/hip_runtime.h>
#include <stdint.h>

typedef __attribute__((ext_vector_type(8))) short s16x8;
typedef __attribute__((ext_vector_type(4))) float f32x4;
typedef unsigned short u16;

#define DEV static __device__ __forceinline__

DEV f32x4 mfma16(s16x8 a, s16x8 b, f32x4 c) {
    return __builtin_amdgcn_mfma_f32_16x16x32_bf16(a, b, c, 0, 0, 0);
}

DEV void gld16(const void* g, void* l) {
    __builtin_amdgcn_global_load_lds(
        (const __attribute__((address_space(1))) void*)g,
        (__attribute__((address_space(3))) void*)l, 16, 0, 0);
}

DEV u16 f2bf(float x) {
    union { float f; unsigned u; } v; v.f = x;
    unsigned r = v.u + 0x7FFFu + ((v.u >> 16) & 1u);
    return (u16)(r >> 16);
}
DEV float bf2f(u16 h) { return __uint_as_float(((unsigned)h) << 16); }

#define SBAR() do { __builtin_amdgcn_sched_barrier(0); __builtin_amdgcn_s_barrier(); __builtin_amdgcn_sched_barrier(0); } while (0)
#define LGKM0() do { asm volatile("s_waitcnt lgkmcnt(0)" ::: "memory"); __builtin_amdgcn_sched_barrier(0); } while (0)

// ---------------- weight / input conversion ----------------
struct WPtrs { const float* p[16]; };

__global__ void k_conv_w(WPtrs wp, u16* wd, u16* wq) {
    int t = blockIdx.x * 256 + threadIdx.x;
    int mat = t >> 14;
    int e = (t & 16383) << 2;
    const float* s = wp.p[mat] + e;
    u16* d = (mat < 8 ? wd + mat * 65536 : wq + (mat - 8) * 65536) + e;
    float4 v = *(const float4*)s;
    d[0] = f2bf(v.x); d[1] = f2bf(v.y); d[2] = f2bf(v.z); d[3] = f2bf(v.w);
}

__global__ void k_conv_x(const float* dn, const float* qn, u16* xd, u16* xq) {
    int t = blockIdx.x * 256 + threadIdx.x;
    int h = t >> 19;
    int e = (t & 524287) << 2;
    const float* s = (h ? qn : dn) + e;
    u16* d = (h ? xq : xd) + e;
    float4 v = *(const float4*)s;
    d[0] = f2bf(v.x); d[1] = f2bf(v.y); d[2] = f2bf(v.z); d[3] = f2bf(v.w);
}

// ---------------- projection GEMM: out = X @ W^T ----------------
__global__ __launch_bounds__(256, 1) void k_proj(const u16* xd, const u16* xq,
        const u16* wdm, const u16* wqm, u16* tokd, u16* tokq, u16* vtd, u16* vtq) {
    __shared__ __align__(16) char smem[16384];
    char* As = smem; char* Bs = smem + 8192;
    const int lane = threadIdx.x & 63, wid = threadIdx.x >> 6;
    const int z = blockIdx.z, grp = z >> 3, w = z & 7;
    const u16* X = grp ? xq : xd;
    const u16* W = (grp ? wqm : wdm) + w * 65536;
    const int m0 = blockIdx.x * 128, n0 = blockIdx.y * 128;
    const int wr = wid >> 1, wc = wid & 1;
    const int rl = lane & 15, g = lane >> 4;
    const f32x4 fz = {0.f, 0.f, 0.f, 0.f};
    f32x4 acc[4][4];
#pragma unroll
    for (int i = 0; i < 4; ++i)
#pragma unroll
        for (int j = 0; j < 4; ++j) acc[i][j] = fz;

    for (int kt = 0; kt < 8; ++kt) {
#pragma unroll
        for (int t = 0; t < 2; ++t) {
            int iid = wid * 2 + t;
            int ldso = iid * 1024 + lane * 16;
            int row = ldso >> 6, inrow = ldso & 63;
            int src = inrow ^ ((row & 3) << 4);
            gld16((const char*)X + ((size_t)(m0 + row) * 512 + kt * 64 + src), As + iid * 1024);
            gld16((const char*)W + ((size_t)(n0 + row) * 512 + kt * 64 + src), Bs + iid * 1024);
        }
        __syncthreads();
        s16x8 av[4], bv[4];
#pragma unroll
        for (int rf = 0; rf < 4; ++rf) {
            int row = wr * 64 + rf * 16 + rl;
            av[rf] = *(const s16x8*)(As + row * 64 + ((g * 16) ^ ((row & 3) << 4)));
        }
#pragma unroll
        for (int cf = 0; cf < 4; ++cf) {
            int row = wc * 64 + cf * 16 + rl;
            bv[cf] = *(const s16x8*)(Bs + row * 64 + ((g * 16) ^ ((row & 3) << 4)));
        }
#pragma unroll
        for (int rf = 0; rf < 4; ++rf)
#pragma unroll
            for (int cf = 0; cf < 4; ++cf)
                acc[rf][cf] = mfma16(av[rf], bv[cf], acc[rf][cf]);
        __syncthreads();
    }
    if (w < 4) {
        u16* out = (grp ? tokq : tokd) + (size_t)w * 2097152;
#pragma unroll
        for (int rf = 0; rf < 4; ++rf)
#pragma unroll
            for (int cf = 0; cf < 4; ++cf) {
                int n = n0 + wc * 64 + cf * 16 + rl;
                int m = m0 + wr * 64 + rf * 16 + g * 4;
#pragma unroll
                for (int r = 0; r < 4; ++r)
                    out[(size_t)(m + r) * 256 + n] = f2bf(acc[rf][cf][r]);
            }
    } else {
        u16* out = (grp ? vtq : vtd) + (size_t)(w - 4) * 2097152;
#pragma unroll
        for (int rf = 0; rf < 4; ++rf)
#pragma unroll
            for (int cf = 0; cf < 4; ++cf) {
                int n = n0 + wc * 64 + cf * 16 + rl;
                int m = m0 + wr * 64 + rf * 16 + g * 4;
                int b = m >> 10, tok = m & 1023;
                unsigned lo = (unsigned)f2bf(acc[rf][cf][0]) | ((unsigned)f2bf(acc[rf][cf][1]) << 16);
                unsigned hi = (unsigned)f2bf(acc[rf][cf][2]) | ((unsigned)f2bf(acc[rf][cf][3]) << 16);
                uint2 u; u.x = lo; u.y = hi;
                *(uint2*)(out + ((size_t)(b * 256 + n)) * 1024 + tok) = u;
            }
    }
}

// ---------------- fused masked attention (one quadrant per z) ----------------
struct PhaseCfg {
    const u16* Q; const u16* K; const u16* Vl; const u16* Vr;
    const int* rm; const int* cm;
    int roff, coff; float scale;
    float* po; float* nbOut;
};

// BM=32, j-tile=32, 4 waves in 2x2 (ws=row strip, wc=col half).
// Single K buffer (M barrier = WAR fence); V direct from global (channel-major);
// XCD-swizzled block mapping clusters each (b,quadrant)'s 32 blocks on one XCD.
// launch_bounds(256,3): VGPR cap 170 -- round 4's (256,4) cap 128 caused
// catastrophic scratch spill (VGPR=64 + 2.1GB scratch writes).
__global__ __launch_bounds__(256, 3) void k_attn(PhaseCfg c0, PhaseCfg c1,
        PhaseCfg c2, PhaseCfg c3, const int* ner, const int* graph) {
    // bijective XCD swizzle: lin%8 = XCD (round-robin dispatch assumption).
    // Each XCD gets 4 (b,quadrant) pairs x 32 i-blocks -> K/V shared in its L2.
    const int lin = blockIdx.x + 32 * blockIdx.y + 256 * blockIdx.z;
    const int xcd = lin & 7, kk0 = lin >> 3;
    const int p = xcd * 4 + (kk0 >> 5);
    const int i0 = (kk0 & 31) * 32;
    const int z = p >> 3, b = p & 7;
    const PhaseCfg c = z == 0 ? c0 : z == 1 ? c1 : z == 2 ? c2 : c3;
    const int lane = threadIdx.x & 63, w = threadIdx.x >> 6;
    const int ws = w >> 1, wc = w & 1;
    const int rl = lane & 15, g = lane >> 4;

    __shared__ __align__(16) char smem[22400];
    u16* Pls = (u16*)(smem + 16384);
    u16* Prs = (u16*)(smem + 18944);
    float* mxS  = (float*)(smem + 21504);
    float* rsS  = (float*)(smem + 21760);
    float* dpS  = (float*)(smem + 21888);
    float* nbpS = (float*)(smem + 22144);

    // Q fragments: rows i0+ws*16+rl, k = kf*32 + g*8 .. +8 (bf16 always)
    s16x8 qf[8];
    {
        const u16* Qb = c.Q + (size_t)(b * 1024 + i0 + ws * 16 + rl) * 256 + g * 8;
#pragma unroll
        for (int kf = 0; kf < 8; ++kf) qf[kf] = *(const s16x8*)(Qb + kf * 32);
    }
    const int iqb = i0 + ws * 16 + g * 4;
    int rmv[4];
#pragma unroll
    for (int r = 0; r < 4; ++r)
        rmv[r] = c.rm[b * 1024 + iqb + r] != 0;

    const size_t mb0 = ((size_t)(b * 2048 + c.roff + iqb)) * 2048 + c.coff + wc * 16;
    const int* nrb = ner + mb0;
    const int* grb = graph + mb0;
    const int* cmp = c.cm + b * 1024 + wc * 16;

    const f32x4 fz = {0.f,0.f,0.f,0.f};
    f32x4 accl[2][4], accr[2][4];
#pragma unroll
    for (int i = 0; i < 2; ++i)
#pragma unroll
        for (int j = 0; j < 4; ++j) { accl[i][j] = fz; accr[i][j] = fz; }
    float mrow[4] = {-1e30f,-1e30f,-1e30f,-1e30f};
    float dden[4] = {0.f,0.f,0.f,0.f};
    float nbc[4]  = {0.f,0.f,0.f,0.f};

    const char* Kg  = (const char*)c.K  + (size_t)b * 524288;
    const char* Vlg = (const char*)c.Vl + (size_t)b * 524288;
    const char* Vrg = (const char*)c.Vr + (size_t)b * 524288;

    auto STAGE_K = [&](int j0) {
#pragma unroll
        for (int t = 0; t < 4; ++t) {
            int iid = w * 4 + t;
            int ldso = iid * 1024 + lane * 16;
            int row = ldso >> 9, inrow = ldso & 511;
            int src = inrow ^ ((row & 7) << 4);
            gld16(Kg + ((size_t)(j0 + row) * 512 + src), smem + iid * 1024);
        }
    };

    int mn[4], mg[4], mc;
    auto MLOAD = [&](int j0) {
#pragma unroll
        for (int r = 0; r < 4; ++r) {
            mn[r] = nrb[r * 2048 + j0 + rl];
            mg[r] = grb[r * 2048 + j0 + rl];
        }
        mc = cmp[j0 + rl];
    };

    STAGE_K(0);
    MLOAD(0);

#pragma unroll 1
    for (int jt = 0; jt < 32; ++jt) {
        const int j0 = jt * 32;

        // V fragments direct from global (channel-major, 16B coalesced)
        s16x8 vl[4], vr[4];
#pragma unroll
        for (int cf = 0; cf < 4; ++cf) {
            size_t off = (size_t)(w * 64 + cf * 16 + rl) * 2048 + (size_t)(j0 + g * 8) * 2;
            vl[cf] = *(const s16x8*)(Vlg + off);
            vr[cf] = *(const s16x8*)(Vrg + off);
        }
        // queue: STAGE_K(jt)=4 (oldest), MLOAD(jt)=9, V=8 -> drain K only
        asm volatile("s_waitcnt vmcnt(17)" ::: "memory");
        SBAR();   // (A) K tile visible

        // S = Q K^T : wave's 16 rows x 16 cols (cols wc*16..+16)
        f32x4 s0 = fz;
#pragma unroll
        for (int kk = 0; kk < 8; ++kk) {
            int jr = wc * 16 + rl;
            s16x8 b0 = *(const s16x8*)(smem + jr * 512 + ((kk * 64 + g * 16) ^ ((jr & 7) << 4)));
            s0 = mfma16(qf[kk], b0, s0);
        }

        const int jq = j0 + wc * 16 + rl;
        const int cmv = mc != 0;
        float sv[4]; int lm[4], rm2[4];
#pragma unroll
        for (int r = 0; r < 4; ++r) {
            int nv = mn[r] != 0, gv = mg[r] != 0;
            int v0 = rmv[r] & cmv & nv;
            int e0 = v0 & (int)((c.roff + iqb + r) != (c.coff + jq));
            sv[r] = v0 ? s0[r] * c.scale : -1e30f;
            lm[r] = e0 & gv;  rm2[r] = e0 & (gv ^ 1);
            nbc[r] += (float)e0;
        }
        float tl[4];
#pragma unroll
        for (int r = 0; r < 4; ++r) {
            float t = sv[r];
            t = fmaxf(t, __shfl_xor(t, 1));
            t = fmaxf(t, __shfl_xor(t, 2));
            t = fmaxf(t, __shfl_xor(t, 4));
            t = fmaxf(t, __shfl_xor(t, 8));
            tl[r] = t;
        }
        if (rl == 0) {
            f32x4 tv = {tl[0], tl[1], tl[2], tl[3]};
            *(f32x4*)(mxS + wc * 32 + ws * 16 + g * 4) = tv;
        }
        LGKM0();
        SBAR();   // (M) maxima visible; K reads all done -> WAR fence

        if (jt < 31) STAGE_K(j0 + 32);   // single buffer, safe after M

        f32x4 mo = *(const f32x4*)(mxS + (wc ^ 1) * 32 + ws * 16 + g * 4);
        float rsv[4];
#pragma unroll
        for (int r = 0; r < 4; ++r) {
            float mn2 = fmaxf(mrow[r], fmaxf(tl[r], mo[r]));
            rsv[r] = __expf(mrow[r] - mn2);
            mrow[r] = mn2;
            float e0 = __expf(sv[r] - mn2);
            dden[r] = dden[r] * rsv[r] + e0;
            int prow = ws * 16 + g * 4 + r;
            Pls[prow * 40 + wc * 16 + rl] = lm[r]  ? f2bf(e0) : (u16)0;
            Prs[prow * 40 + wc * 16 + rl] = rm2[r] ? f2bf(e0) : (u16)0;
        }
        if (rl == 0 && wc == 0) {
            f32x4 rv = {rsv[0], rsv[1], rsv[2], rsv[3]};
            *(f32x4*)(rsS + ws * 16 + g * 4) = rv;
        }
        LGKM0();
        SBAR();   // (B) P + rescale visible

        if (jt < 31) MLOAD(j0 + 32);

        // PV: wave's 64-channel slice over all 32 rows
        f32x4 rs4[2];
#pragma unroll
        for (int rf = 0; rf < 2; ++rf) rs4[rf] = *(const f32x4*)(rsS + rf * 16 + g * 4);
#pragma unroll
        for (int rf = 0; rf < 2; ++rf)
#pragma unroll
            for (int cf = 0; cf < 4; ++cf) { accl[rf][cf] *= rs4[rf]; accr[rf][cf] *= rs4[rf]; }
        s16x8 pa[2], pb[2];
#pragma unroll
        for (int rf = 0; rf < 2; ++rf) {
            pa[rf] = *(const s16x8*)((char*)Pls + (rf * 16 + rl) * 80 + g * 16);
            pb[rf] = *(const s16x8*)((char*)Prs + (rf * 16 + rl) * 80 + g * 16);
        }
#pragma unroll
        for (int rf = 0; rf < 2; ++rf)
#pragma unroll
            for (int cf = 0; cf < 4; ++cf) {
                accl[rf][cf] = mfma16(pa[rf], vl[cf], accl[rf][cf]);
                accr[rf][cf] = mfma16(pb[rf], vr[cf], accr[rf][cf]);
            }
    }

    // reduce row stats over rl, publish per col-half
#pragma unroll
    for (int r = 0; r < 4; ++r) {
        float d = dden[r];
        d += __shfl_xor(d, 1); d += __shfl_xor(d, 2); d += __shfl_xor(d, 4); d += __shfl_xor(d, 8);
        dden[r] = d;
        float nn = nbc[r];
        nn += __shfl_xor(nn, 1); nn += __shfl_xor(nn, 2); nn += __shfl_xor(nn, 4); nn += __shfl_xor(nn, 8);
        nbc[r] = nn;
    }
    if (rl == 0) {
        f32x4 dv = {dden[0], dden[1], dden[2], dden[3]};
        *(f32x4*)(dpS + wc * 32 + ws * 16 + g * 4) = dv;
        f32x4 nv = {nbc[0], nbc[1], nbc[2], nbc[3]};
        *(f32x4*)(nbpS + wc * 32 + ws * 16 + g * 4) = nv;
    }
    __syncthreads();

    if (rl == 0 && wc == 0) {
        f32x4 n0 = *(const f32x4*)(nbpS + ws * 16 + g * 4);
        f32x4 n1 = *(const f32x4*)(nbpS + 32 + ws * 16 + g * 4);
        f32x4 nt = n0 + n1;
        *(f32x4*)(c.nbOut + b * 1024 + i0 + ws * 16 + g * 4) = nt;
    }
#pragma unroll
    for (int rf = 0; rf < 2; ++rf) {
        f32x4 d0 = *(const f32x4*)(dpS + rf * 16 + g * 4);
        f32x4 d1 = *(const f32x4*)(dpS + 32 + rf * 16 + g * 4);
        f32x4 dt = d0 + d1;
#pragma unroll
        for (int cf = 0; cf < 4; ++cf) {
            int col = w * 64 + cf * 16 + rl;
#pragma unroll
            for (int r = 0; r < 4; ++r) {
                int row = i0 + rf * 16 + g * 4 + r;
                size_t oi = (size_t)(b * 1024 + row) * 256 + col;
                float inv = dt[r] > 0.f ? 1.f / dt[r] : 0.f;
                c.po[oi] = (accl[rf][cf][r] + accr[rf][cf][r]) * inv;
            }
        }
    }
}

// ---------------- combine: out = relu(self + bias + (pA+pB)/max(nbA+nbB,1)) ----------------
struct FinCfg {
    const float* pA; const float* pB; const float* nbA; const float* nbB;
    const u16* self; float* out;
};

__global__ __launch_bounds__(256) void k_fin(FinCfg f0, FinCfg f1, const float* bias) {
    const FinCfg f = blockIdx.y ? f1 : f0;
    int row = blockIdx.x * 4 + (threadIdx.x >> 6);   // 0..8191 (b*1024+i)
    int ch = (threadIdx.x & 63) * 4;
    size_t oi = (size_t)row * 256 + ch;
    float inv = 1.f / fmaxf(f.nbA[row] + f.nbB[row], 1.f);
    f32x4 a = *(const f32x4*)(f.pA + oi);
    f32x4 p = *(const f32x4*)(f.pB + oi);
    f32x4 bi = *(const f32x4*)(bias + ch);
    uint2 sv = *(const uint2*)(f.self + oi);
    float s[4] = { bf2f((u16)(sv.x & 0xffff)), bf2f((u16)(sv.x >> 16)),
                   bf2f((u16)(sv.y & 0xffff)), bf2f((u16)(sv.y >> 16)) };
    f32x4 o;
#pragma unroll
    for (int k = 0; k < 4; ++k)
        o[k] = fmaxf(s[k] + bi[k] + (a[k] + p[k]) * inv, 0.f);
    *(f32x4*)(f.out + oi) = o;
}

// ---------------- host ----------------
extern "C" void kernel_launch(void* const* d_in, const int* in_sizes, int n_in,
                              void* d_out, int out_size, void* d_ws, size_t ws_size,
                              hipStream_t stream) {
    (void)in_sizes; (void)n_in; (void)out_size; (void)ws_size;
    const float* d_node = (const float*)d_in[0];
    const float* q_node = (const float*)d_in[1];
    const float* b_self = (const float*)d_in[9];
    const int* dm = (const int*)d_in[18];
    const int* qm = (const int*)d_in[19];
    const int* ner = (const int*)d_in[20];
    const int* graph = (const int*)d_in[21];

    char* ws = (char*)d_ws;
    const size_t MB = 1024 * 1024;
    u16* xd   = (u16*)(ws + 0 * MB);
    u16* xq   = (u16*)(ws + 4 * MB);
    u16* wdm  = (u16*)(ws + 8 * MB);
    u16* wqm  = (u16*)(ws + 9 * MB);
    u16* tokd = (u16*)(ws + 10 * MB);     // [Qd, Kd, Kqd, SelfD]
    u16* tokq = (u16*)(ws + 26 * MB);     // [Qq, Kq, Kdq, SelfQ]
    u16* vtd  = (u16*)(ws + 42 * MB);     // [ddl, ddr, qdl, qdr] channel-major
    u16* vtq  = (u16*)(ws + 58 * MB);     // [qql, qqr, dql, dqr]
    float* nbdd = (float*)(ws + 74 * MB);
    float* nbqq = (float*)(ws + 74 * MB + 32768);
    float* nbdq = (float*)(ws + 74 * MB + 65536);
    float* nbqd = (float*)(ws + 74 * MB + 98304);
    float* Pdq  = (float*)(ws + 75 * MB);     // 8 MB
    float* Pqd  = (float*)(ws + 83 * MB);     // 8 MB

    float* outd = (float*)d_out;              // also holds Pdd partial
    float* outq = outd + 2097152;             // also holds Pqq partial

    WPtrs wp;
    wp.p[0]  = (const float*)d_in[2];   // W_dq_query -> Qd
    wp.p[1]  = (const float*)d_in[3];   // W_dk_key   -> Kd
    wp.p[2]  = (const float*)d_in[7];   // W_qd_fc    -> Kqd
    wp.p[3]  = (const float*)d_in[8];   // W_self     -> SelfD
    wp.p[4]  = (const float*)d_in[10];  // W_dd_l
    wp.p[5]  = (const float*)d_in[14];  // W_dd_r
    wp.p[6]  = (const float*)d_in[13];  // W_qd_l
    wp.p[7]  = (const float*)d_in[17];  // W_qd_r
    wp.p[8]  = (const float*)d_in[4];   // W_qq_query -> Qq
    wp.p[9]  = (const float*)d_in[5];   // W_qk_key   -> Kq
    wp.p[10] = (const float*)d_in[6];   // W_dq_fc    -> Kdq
    wp.p[11] = (const float*)d_in[8];   // W_self     -> SelfQ
    wp.p[12] = (const float*)d_in[11];  // W_qq_l
    wp.p[13] = (const float*)d_in[15];  // W_qq_r
    wp.p[14] = (const float*)d_in[12];  // W_dq_l
    wp.p[15] = (const float*)d_in[16];  // W_dq_r

    k_conv_w<<<1024, 256, 0, stream>>>(wp, wdm, wqm);
    k_conv_x<<<4096, 256, 0, stream>>>(d_node, q_node, xd, xq);
    k_proj<<<dim3(64, 2, 16), 256, 0, stream>>>(xd, xq, wdm, wqm, tokd, tokq, vtd, vtq);

    const size_t M2 = 2097152;
    PhaseCfg dd = { tokd,          tokd + M2,     vtd,          vtd + M2,
                    dm, dm, 0, 0, 0.0625f, outd, nbdd };
    PhaseCfg qq = { tokq,          tokq + M2,     vtq,          vtq + M2,
                    qm, qm, 1024, 1024, 0.0625f, outq, nbqq };
    PhaseCfg dq = { xd,            tokq + 2 * M2, vtq + 2 * M2, vtq + 3 * M2,
                    dm, qm, 0, 1024, 1.0f, Pdq, nbdq };
    PhaseCfg qd = { xq,            tokd + 2 * M2, vtd + 2 * M2, vtd + 3 * M2,
                    qm, dm, 1024, 0, 1.0f, Pqd, nbqd };
    k_attn<<<dim3(32, 8, 4), 256, 0, stream>>>(dd, qq, dq, qd, ner, graph);

    FinCfg fd = { outd, Pdq, nbdd, nbdq, tokd + 3 * M2, outd };
    FinCfg fq = { outq, Pqd, nbqq, nbqd, tokq + 3 * M2, outq };
    k_fin<<<dim3(2048, 2), 256, 0, stream>>>(fd, fq, b_self);
}

// Round 6
// 530.775 us; speedup vs baseline: 2.3452x; 1.9309x over previous
//
#include <hip/hip_runtime.h>
#include <stdint.h>

typedef __attribute__((ext_vector_type(8))) short s16x8;
typedef __attribute__((ext_vector_type(4))) float f32x4;
typedef unsigned short u16;

#define DEV static __device__ __forceinline__

DEV f32x4 mfma16(s16x8 a, s16x8 b, f32x4 c) {
    return __builtin_amdgcn_mfma_f32_16x16x32_bf16(a, b, c, 0, 0, 0);
}

DEV void gld16(const void* g, void* l) {
    __builtin_amdgcn_global_load_lds(
        (const __attribute__((address_space(1))) void*)g,
        (__attribute__((address_space(3))) void*)l, 16, 0, 0);
}

DEV u16 f2bf(float x) {
    union { float f; unsigned u; } v; v.f = x;
    unsigned r = v.u + 0x7FFFu + ((v.u >> 16) & 1u);
    return (u16)(r >> 16);
}
DEV float bf2f(u16 h) { return __uint_as_float(((unsigned)h) << 16); }

#define SBAR() do { __builtin_amdgcn_sched_barrier(0); __builtin_amdgcn_s_barrier(); __builtin_amdgcn_sched_barrier(0); } while (0)
#define LGKM0() do { asm volatile("s_waitcnt lgkmcnt(0)" ::: "memory"); __builtin_amdgcn_sched_barrier(0); } while (0)

// ---------------- weight / input conversion ----------------
struct WPtrs { const float* p[16]; };

__global__ void k_conv_w(WPtrs wp, u16* wd, u16* wq) {
    int t = blockIdx.x * 256 + threadIdx.x;
    int mat = t >> 14;
    int e = (t & 16383) << 2;
    const float* s = wp.p[mat] + e;
    u16* d = (mat < 8 ? wd + mat * 65536 : wq + (mat - 8) * 65536) + e;
    float4 v = *(const float4*)s;
    d[0] = f2bf(v.x); d[1] = f2bf(v.y); d[2] = f2bf(v.z); d[3] = f2bf(v.w);
}

__global__ void k_conv_x(const float* dn, const float* qn, u16* xd, u16* xq) {
    int t = blockIdx.x * 256 + threadIdx.x;
    int h = t >> 19;
    int e = (t & 524287) << 2;
    const float* s = (h ? qn : dn) + e;
    u16* d = (h ? xq : xd) + e;
    float4 v = *(const float4*)s;
    d[0] = f2bf(v.x); d[1] = f2bf(v.y); d[2] = f2bf(v.z); d[3] = f2bf(v.w);
}

// ---------------- projection GEMM: out = X @ W^T ----------------
__global__ __launch_bounds__(256, 1) void k_proj(const u16* xd, const u16* xq,
        const u16* wdm, const u16* wqm, u16* tokd, u16* tokq, u16* vtd, u16* vtq) {
    __shared__ __align__(16) char smem[16384];
    char* As = smem; char* Bs = smem + 8192;
    const int lane = threadIdx.x & 63, wid = threadIdx.x >> 6;
    const int z = blockIdx.z, grp = z >> 3, w = z & 7;
    const u16* X = grp ? xq : xd;
    const u16* W = (grp ? wqm : wdm) + w * 65536;
    const int m0 = blockIdx.x * 128, n0 = blockIdx.y * 128;
    const int wr = wid >> 1, wc = wid & 1;
    const int rl = lane & 15, g = lane >> 4;
    const f32x4 fz = {0.f, 0.f, 0.f, 0.f};
    f32x4 acc[4][4];
#pragma unroll
    for (int i = 0; i < 4; ++i)
#pragma unroll
        for (int j = 0; j < 4; ++j) acc[i][j] = fz;

    for (int kt = 0; kt < 8; ++kt) {
#pragma unroll
        for (int t = 0; t < 2; ++t) {
            int iid = wid * 2 + t;
            int ldso = iid * 1024 + lane * 16;
            int row = ldso >> 6, inrow = ldso & 63;
            int src = inrow ^ ((row & 3) << 4);
            gld16((const char*)X + ((size_t)(m0 + row) * 512 + kt * 64 + src), As + iid * 1024);
            gld16((const char*)W + ((size_t)(n0 + row) * 512 + kt * 64 + src), Bs + iid * 1024);
        }
        __syncthreads();
        s16x8 av[4], bv[4];
#pragma unroll
        for (int rf = 0; rf < 4; ++rf) {
            int row = wr * 64 + rf * 16 + rl;
            av[rf] = *(const s16x8*)(As + row * 64 + ((g * 16) ^ ((row & 3) << 4)));
        }
#pragma unroll
        for (int cf = 0; cf < 4; ++cf) {
            int row = wc * 64 + cf * 16 + rl;
            bv[cf] = *(const s16x8*)(Bs + row * 64 + ((g * 16) ^ ((row & 3) << 4)));
        }
#pragma unroll
        for (int rf = 0; rf < 4; ++rf)
#pragma unroll
            for (int cf = 0; cf < 4; ++cf)
                acc[rf][cf] = mfma16(av[rf], bv[cf], acc[rf][cf]);
        __syncthreads();
    }
    if (w < 4) {
        u16* out = (grp ? tokq : tokd) + (size_t)w * 2097152;
#pragma unroll
        for (int rf = 0; rf < 4; ++rf)
#pragma unroll
            for (int cf = 0; cf < 4; ++cf) {
                int n = n0 + wc * 64 + cf * 16 + rl;
                int m = m0 + wr * 64 + rf * 16 + g * 4;
#pragma unroll
                for (int r = 0; r < 4; ++r)
                    out[(size_t)(m + r) * 256 + n] = f2bf(acc[rf][cf][r]);
            }
    } else {
        u16* out = (grp ? vtq : vtd) + (size_t)(w - 4) * 2097152;
#pragma unroll
        for (int rf = 0; rf < 4; ++rf)
#pragma unroll
            for (int cf = 0; cf < 4; ++cf) {
                int n = n0 + wc * 64 + cf * 16 + rl;
                int m = m0 + wr * 64 + rf * 16 + g * 4;
                int b = m >> 10, tok = m & 1023;
                unsigned lo = (unsigned)f2bf(acc[rf][cf][0]) | ((unsigned)f2bf(acc[rf][cf][1]) << 16);
                unsigned hi = (unsigned)f2bf(acc[rf][cf][2]) | ((unsigned)f2bf(acc[rf][cf][3]) << 16);
                uint2 u; u.x = lo; u.y = hi;
                *(uint2*)(out + ((size_t)(b * 256 + n)) * 1024 + tok) = u;
            }
    }
}

// ---------------- fused masked attention (one quadrant per z) ----------------
struct PhaseCfg {
    const u16* Q; const u16* K; const u16* Vl; const u16* Vr;
    const int* rm; const int* cm;
    int roff, coff; float scale;
    float* po; float* nbOut;
};

// BM=32, TILE_J=64, 16 iterations. 4 waves 2x2 (ws=row strip 16, wc=col half 32).
// Q staged in LDS (reg diet); K single-buffered (staged after M barrier);
// V direct from global channel-major. launch_bounds(256,2): no-spill regime
// (r4/r5 lesson: cap<need -> scratch catastrophe).
// LDS 59264B: Ks@0 (32KB, 64x512B swz), Qs@32768 (16KB, 32x512B swz),
//   Pl@49152 Pr@53760 (32 x 144B), mxS@58368, rsS@58624, dpS@58752, nbpS@59008
__global__ __launch_bounds__(256, 2) void k_attn(PhaseCfg c0, PhaseCfg c1,
        PhaseCfg c2, PhaseCfg c3, const int* ner, const int* graph) {
    const int z = blockIdx.z;
    const PhaseCfg c = z == 0 ? c0 : z == 1 ? c1 : z == 2 ? c2 : c3;
    const int b = blockIdx.y;
    const int i0 = blockIdx.x * 32;
    const int lane = threadIdx.x & 63, w = threadIdx.x >> 6;
    const int ws = w >> 1, wc = w & 1;
    const int rl = lane & 15, g = lane >> 4;

    __shared__ __align__(16) char smem[59264];
    char* Ks = smem;
    char* Qs = smem + 32768;
    u16* Pls = (u16*)(smem + 49152);
    u16* Prs = (u16*)(smem + 53760);
    float* mxS  = (float*)(smem + 58368);
    float* rsS  = (float*)(smem + 58624);
    float* dpS  = (float*)(smem + 58752);
    float* nbpS = (float*)(smem + 59008);

    const char* Kg  = (const char*)c.K  + (size_t)b * 524288;
    const char* Vlg = (const char*)c.Vl + (size_t)b * 524288;
    const char* Vrg = (const char*)c.Vr + (size_t)b * 524288;
    const char* Qg  = (const char*)c.Q + ((size_t)(b * 1024 + i0)) * 512;

    const int iqb = i0 + ws * 16 + g * 4;
    int rmv[4];
#pragma unroll
    for (int r = 0; r < 4; ++r)
        rmv[r] = c.rm[b * 1024 + iqb + r] != 0;

    // mask bases; wave covers cols coff + j0 + wc*32 + {rl, 16+rl}
    const size_t mb0 = ((size_t)(b * 2048 + c.roff + iqb)) * 2048 + c.coff + wc * 32;
    const int* nrb = ner + mb0;
    const int* grb = graph + mb0;
    const int* cmp = c.cm + b * 1024 + wc * 32;

    const f32x4 fz = {0.f,0.f,0.f,0.f};
    f32x4 accl[2][4], accr[2][4];
#pragma unroll
    for (int i = 0; i < 2; ++i)
#pragma unroll
        for (int j = 0; j < 4; ++j) { accl[i][j] = fz; accr[i][j] = fz; }
    float mrow[4] = {-1e30f,-1e30f,-1e30f,-1e30f};
    float dden[4] = {0.f,0.f,0.f,0.f};
    float nbc[4]  = {0.f,0.f,0.f,0.f};

    // stage Q once: 32 rows x 512B, swz ^((row&7)<<4)
    {
#pragma unroll
        for (int t = 0; t < 4; ++t) {
            int iid = w * 4 + t;
            int ldso = iid * 1024 + lane * 16;
            int row = ldso >> 9, inrow = ldso & 511;
            int src = inrow ^ ((row & 7) << 4);
            gld16(Qg + ((size_t)row * 512 + src), Qs + iid * 1024);
        }
    }
    // stage K j-tile (64 rows x 512B = 32KB): 8 gld16 per wave
    auto STAGE_K = [&](int j0) {
#pragma unroll
        for (int t = 0; t < 8; ++t) {
            int iid = w * 8 + t;
            int ldso = iid * 1024 + lane * 16;
            int row = ldso >> 9, inrow = ldso & 511;
            int src = inrow ^ ((row & 7) << 4);
            gld16(Kg + ((size_t)(j0 + row) * 512 + src), Ks + iid * 1024);
        }
    };

    int mn0[4], mn1[4], mg0[4], mg1[4], mc0, mc1;
    auto MLOAD = [&](int j0) {
#pragma unroll
        for (int r = 0; r < 4; ++r) {
            mn0[r] = nrb[r * 2048 + j0 + rl];
            mn1[r] = nrb[r * 2048 + j0 + 16 + rl];
            mg0[r] = grb[r * 2048 + j0 + rl];
            mg1[r] = grb[r * 2048 + j0 + 16 + rl];
        }
        mc0 = cmp[j0 + rl]; mc1 = cmp[j0 + 16 + rl];
    };

    STAGE_K(0);      // 8 (after Q's 4)
    MLOAD(0);        // 18

#pragma unroll 1
    for (int jt = 0; jt < 16; ++jt) {
        const int j0 = jt * 64;

        // V fragments direct from global (channel-major, 16B coalesced): 16 loads
        s16x8 vl[2][4], vr[2][4];
#pragma unroll
        for (int ks = 0; ks < 2; ++ks)
#pragma unroll
            for (int cf = 0; cf < 4; ++cf) {
                size_t off = (size_t)(w * 64 + cf * 16 + rl) * 2048
                           + (size_t)(j0 + ks * 32 + g * 8) * 2;
                vl[ks][cf] = *(const s16x8*)(Vlg + off);
                vr[ks][cf] = *(const s16x8*)(Vrg + off);
            }
        // queue: STAGE(8 [+Q 4 at iter0]) oldest, MLOAD(18), V(16) -> drain stage only
        asm volatile("s_waitcnt vmcnt(34)" ::: "memory");
        SBAR();   // (A) K (and Q) tiles visible

        // S = Q K^T : wave's 16 rows x 64 cols (cols wc*32 + {0..15, 16..31})
        f32x4 s0 = fz, s1 = fz;
        {
            const int qrow = ws * 16 + rl;
            const int jr0 = wc * 32 + rl, jr1 = wc * 32 + 16 + rl;
#pragma unroll
            for (int kk = 0; kk < 8; ++kk) {
                s16x8 qv = *(const s16x8*)(Qs + qrow * 512 + ((kk * 64 + g * 16) ^ ((qrow & 7) << 4)));
                s16x8 b0 = *(const s16x8*)(Ks + jr0 * 512 + ((kk * 64 + g * 16) ^ ((jr0 & 7) << 4)));
                s16x8 b1 = *(const s16x8*)(Ks + jr1 * 512 + ((kk * 64 + g * 16) ^ ((jr1 & 7) << 4)));
                s0 = mfma16(qv, b0, s0);
                s1 = mfma16(qv, b1, s1);
            }
        }

        // masks + local max over this wave's 32 cols
        const int jq0 = j0 + wc * 32 + rl, jq1 = j0 + wc * 32 + 16 + rl;
        const int cv0 = mc0 != 0, cv1 = mc1 != 0;
        float sv0[4], sv1[4];
        int l0[4], l1[4], r0m[4], r1m[4];
#pragma unroll
        for (int r = 0; r < 4; ++r) {
            int iq = c.roff + iqb + r;
            int n0v = mn0[r] != 0, n1v = mn1[r] != 0;
            int g0v = mg0[r] != 0, g1v = mg1[r] != 0;
            int v0 = rmv[r] & cv0 & n0v;
            int v1 = rmv[r] & cv1 & n1v;
            int e0 = v0 & (int)(iq != (c.coff + jq0));
            int e1 = v1 & (int)(iq != (c.coff + jq1));
            sv0[r] = v0 ? s0[r] * c.scale : -1e30f;
            sv1[r] = v1 ? s1[r] * c.scale : -1e30f;
            l0[r] = e0 & g0v;  r0m[r] = e0 & (g0v ^ 1);
            l1[r] = e1 & g1v;  r1m[r] = e1 & (g1v ^ 1);
            nbc[r] += (float)(e0 + e1);
        }
        float tl[4];
#pragma unroll
        for (int r = 0; r < 4; ++r) {
            float t = fmaxf(sv0[r], sv1[r]);
            t = fmaxf(t, __shfl_xor(t, 1));
            t = fmaxf(t, __shfl_xor(t, 2));
            t = fmaxf(t, __shfl_xor(t, 4));
            t = fmaxf(t, __shfl_xor(t, 8));
            tl[r] = t;
        }
        if (rl == 0) {
            f32x4 tv = {tl[0], tl[1], tl[2], tl[3]};
            *(f32x4*)(mxS + wc * 32 + ws * 16 + g * 4) = tv;
        }
        LGKM0();
        SBAR();   // (M) maxima visible; all K/Q reads done -> WAR fence

        if (jt < 15) STAGE_K(j0 + 64);   // single buffer, safe after M

        f32x4 mo = *(const f32x4*)(mxS + (wc ^ 1) * 32 + ws * 16 + g * 4);
        float rsv[4];
#pragma unroll
        for (int r = 0; r < 4; ++r) {
            float mn2 = fmaxf(mrow[r], fmaxf(tl[r], mo[r]));
            rsv[r] = __expf(mrow[r] - mn2);
            mrow[r] = mn2;
            float e0 = __expf(sv0[r] - mn2);
            float e1 = __expf(sv1[r] - mn2);
            dden[r] = dden[r] * rsv[r] + e0 + e1;
            int prow = ws * 16 + g * 4 + r;
            Pls[prow * 72 + wc * 32 + rl]      = l0[r]  ? f2bf(e0) : (u16)0;
            Pls[prow * 72 + wc * 32 + 16 + rl] = l1[r]  ? f2bf(e1) : (u16)0;
            Prs[prow * 72 + wc * 32 + rl]      = r0m[r] ? f2bf(e0) : (u16)0;
            Prs[prow * 72 + wc * 32 + 16 + rl] = r1m[r] ? f2bf(e1) : (u16)0;
        }
        if (rl == 0 && wc == 0) {
            f32x4 rv = {rsv[0], rsv[1], rsv[2], rsv[3]};
            *(f32x4*)(rsS + ws * 16 + g * 4) = rv;
        }
        LGKM0();
        SBAR();   // (B) P + rescale visible

        if (jt < 15) MLOAD(j0 + 64);

        // PV: wave's 64-channel slice over 32 rows, K=64 in 2 slices
        f32x4 rs4[2];
#pragma unroll
        for (int rf = 0; rf < 2; ++rf) rs4[rf] = *(const f32x4*)(rsS + rf * 16 + g * 4);
        bool need = false;
#pragma unroll
        for (int rf = 0; rf < 2; ++rf)
#pragma unroll
            for (int r = 0; r < 4; ++r) need = need || (rs4[rf][r] != 1.0f);
        if (need) {
#pragma unroll
            for (int rf = 0; rf < 2; ++rf)
#pragma unroll
                for (int cf = 0; cf < 4; ++cf) { accl[rf][cf] *= rs4[rf]; accr[rf][cf] *= rs4[rf]; }
        }
        s16x8 pa[2][2], pb[2][2];
#pragma unroll
        for (int rf = 0; rf < 2; ++rf)
#pragma unroll
            for (int ks = 0; ks < 2; ++ks) {
                pa[rf][ks] = *(const s16x8*)((char*)Pls + (rf * 16 + rl) * 144 + ks * 64 + g * 16);
                pb[rf][ks] = *(const s16x8*)((char*)Prs + (rf * 16 + rl) * 144 + ks * 64 + g * 16);
            }
#pragma unroll
        for (int rf = 0; rf < 2; ++rf)
#pragma unroll
            for (int cf = 0; cf < 4; ++cf) {
                accl[rf][cf] = mfma16(pa[rf][0], vl[0][cf], accl[rf][cf]);
                accr[rf][cf] = mfma16(pb[rf][0], vr[0][cf], accr[rf][cf]);
                accl[rf][cf] = mfma16(pa[rf][1], vl[1][cf], accl[rf][cf]);
                accr[rf][cf] = mfma16(pb[rf][1], vr[1][cf], accr[rf][cf]);
            }
    }

    // reduce row stats over rl, publish per col-half
#pragma unroll
    for (int r = 0; r < 4; ++r) {
        float d = dden[r];
        d += __shfl_xor(d, 1); d += __shfl_xor(d, 2); d += __shfl_xor(d, 4); d += __shfl_xor(d, 8);
        dden[r] = d;
        float nn = nbc[r];
        nn += __shfl_xor(nn, 1); nn += __shfl_xor(nn, 2); nn += __shfl_xor(nn, 4); nn += __shfl_xor(nn, 8);
        nbc[r] = nn;
    }
    if (rl == 0) {
        f32x4 dv = {dden[0], dden[1], dden[2], dden[3]};
        *(f32x4*)(dpS + wc * 32 + ws * 16 + g * 4) = dv;
        f32x4 nv = {nbc[0], nbc[1], nbc[2], nbc[3]};
        *(f32x4*)(nbpS + wc * 32 + ws * 16 + g * 4) = nv;
    }
    __syncthreads();

    if (rl == 0 && wc == 0) {
        f32x4 n0 = *(const f32x4*)(nbpS + ws * 16 + g * 4);
        f32x4 n1 = *(const f32x4*)(nbpS + 32 + ws * 16 + g * 4);
        f32x4 nt = n0 + n1;
        *(f32x4*)(c.nbOut + b * 1024 + i0 + ws * 16 + g * 4) = nt;
    }
#pragma unroll
    for (int rf = 0; rf < 2; ++rf) {
        f32x4 d0 = *(const f32x4*)(dpS + rf * 16 + g * 4);
        f32x4 d1 = *(const f32x4*)(dpS + 32 + rf * 16 + g * 4);
        f32x4 dt = d0 + d1;
#pragma unroll
        for (int cf = 0; cf < 4; ++cf) {
            int col = w * 64 + cf * 16 + rl;
#pragma unroll
            for (int r = 0; r < 4; ++r) {
                int row = i0 + rf * 16 + g * 4 + r;
                size_t oi = (size_t)(b * 1024 + row) * 256 + col;
                float inv = dt[r] > 0.f ? 1.f / dt[r] : 0.f;
                c.po[oi] = (accl[rf][cf][r] + accr[rf][cf][r]) * inv;
            }
        }
    }
}

// ---------------- combine: out = relu(self + bias + (pA+pB)/max(nbA+nbB,1)) ----------------
struct FinCfg {
    const float* pA; const float* pB; const float* nbA; const float* nbB;
    const u16* self; float* out;
};

__global__ __launch_bounds__(256) void k_fin(FinCfg f0, FinCfg f1, const float* bias) {
    const FinCfg f = blockIdx.y ? f1 : f0;
    int row = blockIdx.x * 4 + (threadIdx.x >> 6);   // 0..8191 (b*1024+i)
    int ch = (threadIdx.x & 63) * 4;
    size_t oi = (size_t)row * 256 + ch;
    float inv = 1.f / fmaxf(f.nbA[row] + f.nbB[row], 1.f);
    f32x4 a = *(const f32x4*)(f.pA + oi);
    f32x4 p = *(const f32x4*)(f.pB + oi);
    f32x4 bi = *(const f32x4*)(bias + ch);
    uint2 sv = *(const uint2*)(f.self + oi);
    float s[4] = { bf2f((u16)(sv.x & 0xffff)), bf2f((u16)(sv.x >> 16)),
                   bf2f((u16)(sv.y & 0xffff)), bf2f((u16)(sv.y >> 16)) };
    f32x4 o;
#pragma unroll
    for (int k = 0; k < 4; ++k)
        o[k] = fmaxf(s[k] + bi[k] + (a[k] + p[k]) * inv, 0.f);
    *(f32x4*)(f.out + oi) = o;
}

// ---------------- host ----------------
extern "C" void kernel_launch(void* const* d_in, const int* in_sizes, int n_in,
                              void* d_out, int out_size, void* d_ws, size_t ws_size,
                              hipStream_t stream) {
    (void)in_sizes; (void)n_in; (void)out_size; (void)ws_size;
    const float* d_node = (const float*)d_in[0];
    const float* q_node = (const float*)d_in[1];
    const float* b_self = (const float*)d_in[9];
    const int* dm = (const int*)d_in[18];
    const int* qm = (const int*)d_in[19];
    const int* ner = (const int*)d_in[20];
    const int* graph = (const int*)d_in[21];

    char* ws = (char*)d_ws;
    const size_t MB = 1024 * 1024;
    u16* xd   = (u16*)(ws + 0 * MB);
    u16* xq   = (u16*)(ws + 4 * MB);
    u16* wdm  = (u16*)(ws + 8 * MB);
    u16* wqm  = (u16*)(ws + 9 * MB);
    u16* tokd = (u16*)(ws + 10 * MB);     // [Qd, Kd, Kqd, SelfD]
    u16* tokq = (u16*)(ws + 26 * MB);     // [Qq, Kq, Kdq, SelfQ]
    u16* vtd  = (u16*)(ws + 42 * MB);     // [ddl, ddr, qdl, qdr] channel-major
    u16* vtq  = (u16*)(ws + 58 * MB);     // [qql, qqr, dql, dqr]
    float* nbdd = (float*)(ws + 74 * MB);
    float* nbqq = (float*)(ws + 74 * MB + 32768);
    float* nbdq = (float*)(ws + 74 * MB + 65536);
    float* nbqd = (float*)(ws + 74 * MB + 98304);
    float* Pdq  = (float*)(ws + 75 * MB);     // 8 MB
    float* Pqd  = (float*)(ws + 83 * MB);     // 8 MB

    float* outd = (float*)d_out;              // also holds Pdd partial
    float* outq = outd + 2097152;             // also holds Pqq partial

    WPtrs wp;
    wp.p[0]  = (const float*)d_in[2];   // W_dq_query -> Qd
    wp.p[1]  = (const float*)d_in[3];   // W_dk_key   -> Kd
    wp.p[2]  = (const float*)d_in[7];   // W_qd_fc    -> Kqd
    wp.p[3]  = (const float*)d_in[8];   // W_self     -> SelfD
    wp.p[4]  = (const float*)d_in[10];  // W_dd_l
    wp.p[5]  = (const float*)d_in[14];  // W_dd_r
    wp.p[6]  = (const float*)d_in[13];  // W_qd_l
    wp.p[7]  = (const float*)d_in[17];  // W_qd_r
    wp.p[8]  = (const float*)d_in[4];   // W_qq_query -> Qq
    wp.p[9]  = (const float*)d_in[5];   // W_qk_key   -> Kq
    wp.p[10] = (const float*)d_in[6];   // W_dq_fc    -> Kdq
    wp.p[11] = (const float*)d_in[8];   // W_self     -> SelfQ
    wp.p[12] = (const float*)d_in[11];  // W_qq_l
    wp.p[13] = (const float*)d_in[15];  // W_qq_r
    wp.p[14] = (const float*)d_in[12];  // W_dq_l
    wp.p[15] = (const float*)d_in[16];  // W_dq_r

    k_conv_w<<<1024, 256, 0, stream>>>(wp, wdm, wqm);
    k_conv_x<<<4096, 256, 0, stream>>>(d_node, q_node, xd, xq);
    k_proj<<<dim3(64, 2, 16), 256, 0, stream>>>(xd, xq, wdm, wqm, tokd, tokq, vtd, vtq);

    const size_t M2 = 2097152;
    PhaseCfg dd = { tokd,          tokd + M2,     vtd,          vtd + M2,
                    dm, dm, 0, 0, 0.0625f, outd, nbdd };
    PhaseCfg qq = { tokq,          tokq + M2,     vtq,          vtq + M2,
                    qm, qm, 1024, 1024, 0.0625f, outq, nbqq };
    PhaseCfg dq = { xd,            tokq + 2 * M2, vtq + 2 * M2, vtq + 3 * M2,
                    dm, qm, 0, 1024, 1.0f, Pdq, nbdq };
    PhaseCfg qd = { xq,            tokd + 2 * M2, vtd + 2 * M2, vtd + 3 * M2,
                    qm, dm, 1024, 0, 1.0f, Pqd, nbqd };
    k_attn<<<dim3(32, 8, 4), 256, 0, stream>>>(dd, qq, dq, qd, ner, graph);

    FinCfg fd = { outd, Pdq, nbdd, nbdq, tokd + 3 * M2, outd };
    FinCfg fq = { outq, Pqd, nbqq, nbqd, tokq + 3 * M2, outq };
    k_fin<<<dim3(2048, 2), 256, 0, stream>>>(fd, fq, b_self);
}

// Round 7
// 511.696 us; speedup vs baseline: 2.4326x; 1.0373x over previous
//
#include <hip/hip_runtime.h>
#include <stdint.h>

typedef __attribute__((ext_vector_type(8))) short s16x8;
typedef __attribute__((ext_vector_type(4))) float f32x4;
typedef unsigned short u16;

#define DEV static __device__ __forceinline__

DEV f32x4 mfma16(s16x8 a, s16x8 b, f32x4 c) {
    return __builtin_amdgcn_mfma_f32_16x16x32_bf16(a, b, c, 0, 0, 0);
}

DEV void gld16(const void* g, void* l) {
    __builtin_amdgcn_global_load_lds(
        (const __attribute__((address_space(1))) void*)g,
        (__attribute__((address_space(3))) void*)l, 16, 0, 0);
}

DEV u16 f2bf(float x) {
    union { float f; unsigned u; } v; v.f = x;
    unsigned r = v.u + 0x7FFFu + ((v.u >> 16) & 1u);
    return (u16)(r >> 16);
}
DEV float bf2f(u16 h) { return __uint_as_float(((unsigned)h) << 16); }

#define SBAR() do { __builtin_amdgcn_sched_barrier(0); __builtin_amdgcn_s_barrier(); __builtin_amdgcn_sched_barrier(0); } while (0)
#define LGKM0() do { asm volatile("s_waitcnt lgkmcnt(0)" ::: "memory"); __builtin_amdgcn_sched_barrier(0); } while (0)

// ---------------- weight / input conversion ----------------
struct WPtrs { const float* p[16]; };

__global__ void k_conv_w(WPtrs wp, u16* wd, u16* wq) {
    int t = blockIdx.x * 256 + threadIdx.x;
    int mat = t >> 14;
    int e = (t & 16383) << 2;
    const float* s = wp.p[mat] + e;
    u16* d = (mat < 8 ? wd + mat * 65536 : wq + (mat - 8) * 65536) + e;
    float4 v = *(const float4*)s;
    d[0] = f2bf(v.x); d[1] = f2bf(v.y); d[2] = f2bf(v.z); d[3] = f2bf(v.w);
}

__global__ void k_conv_x(const float* dn, const float* qn, u16* xd, u16* xq) {
    int t = blockIdx.x * 256 + threadIdx.x;
    int h = t >> 19;
    int e = (t & 524287) << 2;
    const float* s = (h ? qn : dn) + e;
    u16* d = (h ? xq : xd) + e;
    float4 v = *(const float4*)s;
    d[0] = f2bf(v.x); d[1] = f2bf(v.y); d[2] = f2bf(v.z); d[3] = f2bf(v.w);
}

// ---------------- mask pre-pass: pack to bit-planes + nb rowsums ----------------
// One thread = one (row, 32-col word). Reads 128B contiguous per array per thread.
// l-bit = e&g, r-bit = e&~g where e = rm*cm*ner minus diagonal; diag validity
// stored per-row (1 bit). nb[row] += popcount(e) via float atomicAdd.
struct QuadCfg {
    const int* rm; const int* cm; int roff, coff, diag;
    unsigned* pl; unsigned* pr; unsigned char* dgp; float* nb;
};

__global__ __launch_bounds__(256) void k_mask(QuadCfg q0, QuadCfg q1, QuadCfg q2, QuadCfg q3,
        const int* ner, const int* graph) {
    const int z = blockIdx.z;
    const QuadCfg c = z == 0 ? q0 : z == 1 ? q1 : z == 2 ? q2 : q3;
    const int b = blockIdx.y;
    const int t = threadIdx.x;
    const int sub = t >> 5, w = t & 31;
    const int i = blockIdx.x * 8 + sub;
    const int rm = c.rm[b * 1024 + i] != 0;
    size_t rowbase = ((size_t)(b * 2048 + c.roff + i)) * 2048 + c.coff + w * 32;
    const int4* np = (const int4*)(ner + rowbase);
    const int4* gp = (const int4*)(graph + rowbase);
    const int4* cp = (const int4*)(c.cm + b * 1024 + w * 32);
    unsigned v = 0, gw = 0;
#pragma unroll
    for (int k = 0; k < 8; ++k) {
        int4 nv = np[k], gv = gp[k], cv = cp[k];
        unsigned bs = k * 4;
        v  |= ((unsigned)(rm & (cv.x != 0) & (nv.x != 0))) << bs;
        v  |= ((unsigned)(rm & (cv.y != 0) & (nv.y != 0))) << (bs + 1);
        v  |= ((unsigned)(rm & (cv.z != 0) & (nv.z != 0))) << (bs + 2);
        v  |= ((unsigned)(rm & (cv.w != 0) & (nv.w != 0))) << (bs + 3);
        gw |= ((unsigned)(gv.x != 0)) << bs;
        gw |= ((unsigned)(gv.y != 0)) << (bs + 1);
        gw |= ((unsigned)(gv.z != 0)) << (bs + 2);
        gw |= ((unsigned)(gv.w != 0)) << (bs + 3);
    }
    unsigned e = v;
    if (c.diag && (i >> 5) == w) {
        e &= ~(1u << (i & 31));
        c.dgp[b * 1024 + i] = (unsigned char)((v >> (i & 31)) & 1u);
    }
    unsigned lb = e & gw, rb = e & ~gw;
    size_t widx = ((size_t)(b * 1024 + i)) * 32 + w;
    c.pl[widx] = lb;
    c.pr[widx] = rb;
    int cnt = __popc(e);
    cnt += __shfl_xor(cnt, 1); cnt += __shfl_xor(cnt, 2);
    cnt += __shfl_xor(cnt, 4); cnt += __shfl_xor(cnt, 8); cnt += __shfl_xor(cnt, 16);
    if (w == 0) atomicAdd(c.nb + b * 1024 + i, (float)cnt);
}

// ---------------- projection GEMM: out = X @ W^T ----------------
__global__ __launch_bounds__(256, 1) void k_proj(const u16* xd, const u16* xq,
        const u16* wdm, const u16* wqm, u16* tokd, u16* tokq, u16* vtd, u16* vtq) {
    __shared__ __align__(16) char smem[16384];
    char* As = smem; char* Bs = smem + 8192;
    const int lane = threadIdx.x & 63, wid = threadIdx.x >> 6;
    const int z = blockIdx.z, grp = z >> 3, w = z & 7;
    const u16* X = grp ? xq : xd;
    const u16* W = (grp ? wqm : wdm) + w * 65536;
    const int m0 = blockIdx.x * 128, n0 = blockIdx.y * 128;
    const int wr = wid >> 1, wc = wid & 1;
    const int rl = lane & 15, g = lane >> 4;
    const f32x4 fz = {0.f, 0.f, 0.f, 0.f};
    f32x4 acc[4][4];
#pragma unroll
    for (int i = 0; i < 4; ++i)
#pragma unroll
        for (int j = 0; j < 4; ++j) acc[i][j] = fz;

    for (int kt = 0; kt < 8; ++kt) {
#pragma unroll
        for (int t = 0; t < 2; ++t) {
            int iid = wid * 2 + t;
            int ldso = iid * 1024 + lane * 16;
            int row = ldso >> 6, inrow = ldso & 63;
            int src = inrow ^ ((row & 3) << 4);
            gld16((const char*)X + ((size_t)(m0 + row) * 512 + kt * 64 + src), As + iid * 1024);
            gld16((const char*)W + ((size_t)(n0 + row) * 512 + kt * 64 + src), Bs + iid * 1024);
        }
        __syncthreads();
        s16x8 av[4], bv[4];
#pragma unroll
        for (int rf = 0; rf < 4; ++rf) {
            int row = wr * 64 + rf * 16 + rl;
            av[rf] = *(const s16x8*)(As + row * 64 + ((g * 16) ^ ((row & 3) << 4)));
        }
#pragma unroll
        for (int cf = 0; cf < 4; ++cf) {
            int row = wc * 64 + cf * 16 + rl;
            bv[cf] = *(const s16x8*)(Bs + row * 64 + ((g * 16) ^ ((row & 3) << 4)));
        }
#pragma unroll
        for (int rf = 0; rf < 4; ++rf)
#pragma unroll
            for (int cf = 0; cf < 4; ++cf)
                acc[rf][cf] = mfma16(av[rf], bv[cf], acc[rf][cf]);
        __syncthreads();
    }
    if (w < 4) {
        u16* out = (grp ? tokq : tokd) + (size_t)w * 2097152;
#pragma unroll
        for (int rf = 0; rf < 4; ++rf)
#pragma unroll
            for (int cf = 0; cf < 4; ++cf) {
                int n = n0 + wc * 64 + cf * 16 + rl;
                int m = m0 + wr * 64 + rf * 16 + g * 4;
#pragma unroll
                for (int r = 0; r < 4; ++r)
                    out[(size_t)(m + r) * 256 + n] = f2bf(acc[rf][cf][r]);
            }
    } else {
        u16* out = (grp ? vtq : vtd) + (size_t)(w - 4) * 2097152;
#pragma unroll
        for (int rf = 0; rf < 4; ++rf)
#pragma unroll
            for (int cf = 0; cf < 4; ++cf) {
                int n = n0 + wc * 64 + cf * 16 + rl;
                int m = m0 + wr * 64 + rf * 16 + g * 4;
                int b = m >> 10, tok = m & 1023;
                unsigned lo = (unsigned)f2bf(acc[rf][cf][0]) | ((unsigned)f2bf(acc[rf][cf][1]) << 16);
                unsigned hi = (unsigned)f2bf(acc[rf][cf][2]) | ((unsigned)f2bf(acc[rf][cf][3]) << 16);
                uint2 u; u.x = lo; u.y = hi;
                *(uint2*)(out + ((size_t)(b * 256 + n)) * 1024 + tok) = u;
            }
    }
}

// ---------------- fused masked attention (one quadrant per z) ----------------
struct PhaseCfg {
    const u16* Q; const u16* K; const u16* Vl; const u16* Vr;
    const unsigned* pl; const unsigned* pr; const unsigned char* dgp;
    float scale; float* po;
};

// BM=32, TILE_J=32. 4 waves 2x2 (ws=row strip 16, wc=col half 16).
// Q in LDS (staged once); K single-buffered (staged after M barrier);
// V direct from global channel-major (vl top, vr after M -- reg diet);
// masks = packed bit-planes (L2/L3-hot), loaded per-iter, nb precomputed.
// LDS 38528B: Ks@0 16K, Qs@16384 16K, Pl@32768 2560, Pr@35328 2560,
//   mxS@37888 256, rsS@38144 128, dpS@38272 256
__global__ __launch_bounds__(256, 3) void k_attn(PhaseCfg c0, PhaseCfg c1,
        PhaseCfg c2, PhaseCfg c3) {
    // bijective XCD swizzle: groups each (b,z)'s 32 i-blocks on one XCD
    const int lin = blockIdx.x + 32 * blockIdx.y + 256 * blockIdx.z;
    const int xcd = lin & 7, kk0 = lin >> 3;
    const int p = xcd * 4 + (kk0 >> 5);
    const int i0 = (kk0 & 31) * 32;
    const int z = p >> 3, b = p & 7;
    const PhaseCfg c = z == 0 ? c0 : z == 1 ? c1 : z == 2 ? c2 : c3;
    const int lane = threadIdx.x & 63, w = threadIdx.x >> 6;
    const int ws = w >> 1, wc = w & 1;
    const int rl = lane & 15, g = lane >> 4;

    __shared__ __align__(16) char smem[38528];
    char* Ks = smem;
    char* Qs = smem + 16384;
    u16* Pls = (u16*)(smem + 32768);
    u16* Prs = (u16*)(smem + 35328);
    float* mxS = (float*)(smem + 37888);
    float* rsS = (float*)(smem + 38144);
    float* dpS = (float*)(smem + 38272);

    const char* Kg  = (const char*)c.K  + (size_t)b * 524288;
    const char* Vlg = (const char*)c.Vl + (size_t)b * 524288;
    const char* Vrg = (const char*)c.Vr + (size_t)b * 524288;
    const char* Qg  = (const char*)c.Q + ((size_t)(b * 1024 + i0)) * 512;

    const int iqb = i0 + ws * 16 + g * 4;
    const unsigned* lpRow = c.pl + ((size_t)(b << 10) + iqb) * 32;
    const unsigned* rpRow = c.pr + ((size_t)(b << 10) + iqb) * 32;

    // stage Q once (4 gld16/wave), rows 32 x 512B swz ^((row&7)<<4)
#pragma unroll
    for (int t = 0; t < 4; ++t) {
        int iid = w * 4 + t;
        int ldso = iid * 1024 + lane * 16;
        int row = ldso >> 9, inrow = ldso & 511;
        int src = inrow ^ ((row & 7) << 4);
        gld16(Qg + ((size_t)row * 512 + src), Qs + iid * 1024);
    }
    auto STAGE_K = [&](int j0) {
#pragma unroll
        for (int t = 0; t < 4; ++t) {
            int iid = w * 4 + t;
            int ldso = iid * 1024 + lane * 16;
            int row = ldso >> 9, inrow = ldso & 511;
            int src = inrow ^ ((row & 7) << 4);
            gld16(Kg + ((size_t)(j0 + row) * 512 + src), Ks + iid * 1024);
        }
    };
    STAGE_K(0);

    // per-row diagonal validity (dd/qq only)
    unsigned dgv[4];
#pragma unroll
    for (int r = 0; r < 4; ++r)
        dgv[r] = c.dgp ? (unsigned)c.dgp[b * 1024 + iqb + r] : 0u;

    const f32x4 fz = {0.f, 0.f, 0.f, 0.f};
    f32x4 accl[2][4], accr[2][4];
#pragma unroll
    for (int i = 0; i < 2; ++i)
#pragma unroll
        for (int j = 0; j < 4; ++j) { accl[i][j] = fz; accr[i][j] = fz; }
    float mrow[4] = {-1e30f, -1e30f, -1e30f, -1e30f};
    float dden[4] = {0.f, 0.f, 0.f, 0.f};

#pragma unroll 1
    for (int jt = 0; jt < 32; ++jt) {
        const int j0 = jt * 32;

        // packed masks for this tile (8 dword loads, L2/L3-hot)
        unsigned lw[4], rw[4];
#pragma unroll
        for (int r = 0; r < 4; ++r) {
            lw[r] = lpRow[r * 32 + jt];
            rw[r] = rpRow[r * 32 + jt];
        }
        // V-left fragments direct from global (channel-major, 16B coalesced)
        s16x8 vl[4];
#pragma unroll
        for (int cf = 0; cf < 4; ++cf) {
            size_t off = (size_t)(w * 64 + cf * 16 + rl) * 2048 + (size_t)(j0 + g * 8) * 2;
            vl[cf] = *(const s16x8*)(Vlg + off);
        }
        // queue: [K4 (+Q4,dg4 at iter0) oldest], masks 8, vl 4 -> drain stage
        asm volatile("s_waitcnt vmcnt(12)" ::: "memory");
        SBAR();   // (A) K (and Q) visible

        // S = Q K^T : wave's 16 rows x 16 cols
        f32x4 s0 = fz;
        {
            const int qrow = ws * 16 + rl;
            const int jr = wc * 16 + rl;
#pragma unroll
            for (int kk = 0; kk < 8; ++kk) {
                s16x8 qv = *(const s16x8*)(Qs + qrow * 512 + ((kk * 64 + g * 16) ^ ((qrow & 7) << 4)));
                s16x8 b0 = *(const s16x8*)(Ks + jr * 512 + ((kk * 64 + g * 16) ^ ((jr & 7) << 4)));
                s0 = mfma16(qv, b0, s0);
            }
        }

        // softmax masking from bits. frag elem: row = iqb+r, col bit = wc*16+rl
        const int bp = wc * 16 + rl;
        float sv[4]; int lm[4], rm2[4];
#pragma unroll
        for (int r = 0; r < 4; ++r) {
            unsigned vw = lw[r] | rw[r];
            int row = iqb + r;
            if (jt == (row >> 5)) vw |= dgv[r] << (row & 31);
            int v0 = (vw >> bp) & 1;
            sv[r] = v0 ? s0[r] * c.scale : -1e30f;
            lm[r] = (lw[r] >> bp) & 1;
            rm2[r] = (rw[r] >> bp) & 1;
        }
        float tl[4];
#pragma unroll
        for (int r = 0; r < 4; ++r) {
            float t = sv[r];
            t = fmaxf(t, __shfl_xor(t, 1));
            t = fmaxf(t, __shfl_xor(t, 2));
            t = fmaxf(t, __shfl_xor(t, 4));
            t = fmaxf(t, __shfl_xor(t, 8));
            tl[r] = t;
        }
        if (rl == 0) {
            f32x4 tv = {tl[0], tl[1], tl[2], tl[3]};
            *(f32x4*)(mxS + wc * 32 + ws * 16 + g * 4) = tv;
        }
        LGKM0();
        SBAR();   // (M) maxima visible; K/Q reads done -> WAR fence

        if (jt < 31) STAGE_K(j0 + 32);   // single buffer, safe after M
        // V-right fragments (consumed late in PV -> latency covered)
        s16x8 vr[4];
#pragma unroll
        for (int cf = 0; cf < 4; ++cf) {
            size_t off = (size_t)(w * 64 + cf * 16 + rl) * 2048 + (size_t)(j0 + g * 8) * 2;
            vr[cf] = *(const s16x8*)(Vrg + off);
        }

        f32x4 mo = *(const f32x4*)(mxS + (wc ^ 1) * 32 + ws * 16 + g * 4);
        float rsv[4];
#pragma unroll
        for (int r = 0; r < 4; ++r) {
            float mn2 = fmaxf(mrow[r], fmaxf(tl[r], mo[r]));
            rsv[r] = __expf(mrow[r] - mn2);
            mrow[r] = mn2;
            float e0 = __expf(sv[r] - mn2);
            dden[r] = dden[r] * rsv[r] + e0;
            int prow = ws * 16 + g * 4 + r;
            Pls[prow * 40 + wc * 16 + rl] = lm[r]  ? f2bf(e0) : (u16)0;
            Prs[prow * 40 + wc * 16 + rl] = rm2[r] ? f2bf(e0) : (u16)0;
        }
        if (rl == 0 && wc == 0) {
            f32x4 rv = {rsv[0], rsv[1], rsv[2], rsv[3]};
            *(f32x4*)(rsS + ws * 16 + g * 4) = rv;
        }
        LGKM0();
        SBAR();   // (B) P + rescale visible

        // PV: wave's 64-channel slice over all 32 rows
        f32x4 rs4[2];
#pragma unroll
        for (int rf = 0; rf < 2; ++rf) rs4[rf] = *(const f32x4*)(rsS + rf * 16 + g * 4);
#pragma unroll
        for (int rf = 0; rf < 2; ++rf)
#pragma unroll
            for (int cf = 0; cf < 4; ++cf) { accl[rf][cf] *= rs4[rf]; accr[rf][cf] *= rs4[rf]; }
        s16x8 pa[2], pb[2];
#pragma unroll
        for (int rf = 0; rf < 2; ++rf) {
            pa[rf] = *(const s16x8*)((char*)Pls + (rf * 16 + rl) * 80 + g * 16);
            pb[rf] = *(const s16x8*)((char*)Prs + (rf * 16 + rl) * 80 + g * 16);
        }
#pragma unroll
        for (int rf = 0; rf < 2; ++rf)
#pragma unroll
            for (int cf = 0; cf < 4; ++cf)
                accl[rf][cf] = mfma16(pa[rf], vl[cf], accl[rf][cf]);
#pragma unroll
        for (int rf = 0; rf < 2; ++rf)
#pragma unroll
            for (int cf = 0; cf < 4; ++cf)
                accr[rf][cf] = mfma16(pb[rf], vr[cf], accr[rf][cf]);
    }

    // reduce denominators over rl, publish per col-half
#pragma unroll
    for (int r = 0; r < 4; ++r) {
        float d = dden[r];
        d += __shfl_xor(d, 1); d += __shfl_xor(d, 2); d += __shfl_xor(d, 4); d += __shfl_xor(d, 8);
        dden[r] = d;
    }
    if (rl == 0) {
        f32x4 dv = {dden[0], dden[1], dden[2], dden[3]};
        *(f32x4*)(dpS + wc * 32 + ws * 16 + g * 4) = dv;
    }
    __syncthreads();

#pragma unroll
    for (int rf = 0; rf < 2; ++rf) {
        f32x4 d0 = *(const f32x4*)(dpS + rf * 16 + g * 4);
        f32x4 d1 = *(const f32x4*)(dpS + 32 + rf * 16 + g * 4);
        f32x4 dt = d0 + d1;
#pragma unroll
        for (int cf = 0; cf < 4; ++cf) {
            int col = w * 64 + cf * 16 + rl;
#pragma unroll
            for (int r = 0; r < 4; ++r) {
                int row = i0 + rf * 16 + g * 4 + r;
                size_t oi = (size_t)(b * 1024 + row) * 256 + col;
                float inv = dt[r] > 0.f ? 1.f / dt[r] : 0.f;
                c.po[oi] = (accl[rf][cf][r] + accr[rf][cf][r]) * inv;
            }
        }
    }
}

// ---------------- combine: out = relu(self + bias + (pA+pB)/max(nb,1)) ----------------
struct FinCfg {
    const float* pA; const float* pB; const float* nb;
    const u16* self; float* out;
};

__global__ __launch_bounds__(256) void k_fin(FinCfg f0, FinCfg f1, const float* bias) {
    const FinCfg f = blockIdx.y ? f1 : f0;
    int row = blockIdx.x * 4 + (threadIdx.x >> 6);
    int ch = (threadIdx.x & 63) * 4;
    size_t oi = (size_t)row * 256 + ch;
    float inv = 1.f / fmaxf(f.nb[row], 1.f);
    f32x4 a = *(const f32x4*)(f.pA + oi);
    f32x4 p = *(const f32x4*)(f.pB + oi);
    f32x4 bi = *(const f32x4*)(bias + ch);
    uint2 sv = *(const uint2*)(f.self + oi);
    float s[4] = { bf2f((u16)(sv.x & 0xffff)), bf2f((u16)(sv.x >> 16)),
                   bf2f((u16)(sv.y & 0xffff)), bf2f((u16)(sv.y >> 16)) };
    f32x4 o;
#pragma unroll
    for (int k = 0; k < 4; ++k)
        o[k] = fmaxf(s[k] + bi[k] + (a[k] + p[k]) * inv, 0.f);
    *(f32x4*)(f.out + oi) = o;
}

// ---------------- host ----------------
extern "C" void kernel_launch(void* const* d_in, const int* in_sizes, int n_in,
                              void* d_out, int out_size, void* d_ws, size_t ws_size,
                              hipStream_t stream) {
    (void)in_sizes; (void)n_in; (void)out_size; (void)ws_size;
    const float* d_node = (const float*)d_in[0];
    const float* q_node = (const float*)d_in[1];
    const float* b_self = (const float*)d_in[9];
    const int* dm = (const int*)d_in[18];
    const int* qm = (const int*)d_in[19];
    const int* ner = (const int*)d_in[20];
    const int* graph = (const int*)d_in[21];

    char* ws = (char*)d_ws;
    const size_t MB = 1024 * 1024;
    u16* xd   = (u16*)(ws + 0 * MB);
    u16* xq   = (u16*)(ws + 4 * MB);
    u16* wdm  = (u16*)(ws + 8 * MB);
    u16* wqm  = (u16*)(ws + 9 * MB);
    u16* tokd = (u16*)(ws + 10 * MB);     // [Qd, Kd, Kqd, SelfD]
    u16* tokq = (u16*)(ws + 26 * MB);     // [Qq, Kq, Kdq, SelfQ]
    u16* vtd  = (u16*)(ws + 42 * MB);     // [ddl, ddr, qdl, qdr] channel-major
    u16* vtq  = (u16*)(ws + 58 * MB);     // [qql, qqr, dql, dqr]
    float* nb_d = (float*)(ws + 74 * MB);               // 32 KB
    float* nb_q = (float*)(ws + 74 * MB + 32768);       // 32 KB
    unsigned char* dgd = (unsigned char*)(ws + 74 * MB + 65536);   // 8 KB
    unsigned char* dgq = (unsigned char*)(ws + 74 * MB + 73728);   // 8 KB
    float* Pdq  = (float*)(ws + 75 * MB);     // 8 MB
    float* Pqd  = (float*)(ws + 83 * MB);     // 8 MB
    unsigned* pl_dd = (unsigned*)(ws + 91 * MB);   // 1 MB each
    unsigned* pl_qq = (unsigned*)(ws + 92 * MB);
    unsigned* pl_dq = (unsigned*)(ws + 93 * MB);
    unsigned* pl_qd = (unsigned*)(ws + 94 * MB);
    unsigned* pr_dd = (unsigned*)(ws + 95 * MB);
    unsigned* pr_qq = (unsigned*)(ws + 96 * MB);
    unsigned* pr_dq = (unsigned*)(ws + 97 * MB);
    unsigned* pr_qd = (unsigned*)(ws + 98 * MB);

    float* outd = (float*)d_out;              // holds Pdd partial, then final
    float* outq = outd + 2097152;             // holds Pqq partial, then final

    WPtrs wp;
    wp.p[0]  = (const float*)d_in[2];   // W_dq_query -> Qd
    wp.p[1]  = (const float*)d_in[3];   // W_dk_key   -> Kd
    wp.p[2]  = (const float*)d_in[7];   // W_qd_fc    -> Kqd
    wp.p[3]  = (const float*)d_in[8];   // W_self     -> SelfD
    wp.p[4]  = (const float*)d_in[10];  // W_dd_l
    wp.p[5]  = (const float*)d_in[14];  // W_dd_r
    wp.p[6]  = (const float*)d_in[13];  // W_qd_l
    wp.p[7]  = (const float*)d_in[17];  // W_qd_r
    wp.p[8]  = (const float*)d_in[4];   // W_qq_query -> Qq
    wp.p[9]  = (const float*)d_in[5];   // W_qk_key   -> Kq
    wp.p[10] = (const float*)d_in[6];   // W_dq_fc    -> Kdq
    wp.p[11] = (const float*)d_in[8];   // W_self     -> SelfQ
    wp.p[12] = (const float*)d_in[11];  // W_qq_l
    wp.p[13] = (const float*)d_in[15];  // W_qq_r
    wp.p[14] = (const float*)d_in[12];  // W_dq_l
    wp.p[15] = (const float*)d_in[16];  // W_dq_r

    (void)hipMemsetAsync(ws + 74 * MB, 0, 65536, stream);   // nb_d + nb_q

    k_conv_w<<<1024, 256, 0, stream>>>(wp, wdm, wqm);
    k_conv_x<<<4096, 256, 0, stream>>>(d_node, q_node, xd, xq);

    QuadCfg mdd = { dm, dm, 0, 0, 1, pl_dd, pr_dd, dgd, nb_d };
    QuadCfg mqq = { qm, qm, 1024, 1024, 1, pl_qq, pr_qq, dgq, nb_q };
    QuadCfg mdq = { dm, qm, 0, 1024, 0, pl_dq, pr_dq, nullptr, nb_d };
    QuadCfg mqd = { qm, dm, 1024, 0, 0, pl_qd, pr_qd, nullptr, nb_q };
    k_mask<<<dim3(128, 8, 4), 256, 0, stream>>>(mdd, mqq, mdq, mqd, ner, graph);

    k_proj<<<dim3(64, 2, 16), 256, 0, stream>>>(xd, xq, wdm, wqm, tokd, tokq, vtd, vtq);

    const size_t M2 = 2097152;
    PhaseCfg dd = { tokd,          tokd + M2,     vtd,          vtd + M2,
                    pl_dd, pr_dd, dgd, 0.0625f, outd };
    PhaseCfg qq = { tokq,          tokq + M2,     vtq,          vtq + M2,
                    pl_qq, pr_qq, dgq, 0.0625f, outq };
    PhaseCfg dq = { xd,            tokq + 2 * M2, vtq + 2 * M2, vtq + 3 * M2,
                    pl_dq, pr_dq, nullptr, 1.0f, Pdq };
    PhaseCfg qd = { xq,            tokd + 2 * M2, vtd + 2 * M2, vtd + 3 * M2,
                    pl_qd, pr_qd, nullptr, 1.0f, Pqd };
    k_attn<<<dim3(32, 8, 4), 256, 0, stream>>>(dd, qq, dq, qd);

    FinCfg fd = { outd, Pdq, nb_d, tokd + 3 * M2, outd };
    FinCfg fq = { outq, Pqd, nb_q, tokq + 3 * M2, outq };
    k_fin<<<dim3(2048, 2), 256, 0, stream>>>(fd, fq, b_self);
}

// Round 8
// 328.506 us; speedup vs baseline: 3.7892x; 1.5576x over previous
//
#include <hip/hip_runtime.h>
#include <stdint.h>

typedef __attribute__((ext_vector_type(8))) short s16x8;
typedef __attribute__((ext_vector_type(4))) float f32x4;
typedef unsigned short u16;

#define DEV static __device__ __forceinline__

DEV f32x4 mfma16(s16x8 a, s16x8 b, f32x4 c) {
    return __builtin_amdgcn_mfma_f32_16x16x32_bf16(a, b, c, 0, 0, 0);
}

DEV void gld16(const void* g, void* l) {
    __builtin_amdgcn_global_load_lds(
        (const __attribute__((address_space(1))) void*)g,
        (__attribute__((address_space(3))) void*)l, 16, 0, 0);
}

DEV u16 f2bf(float x) {
    union { float f; unsigned u; } v; v.f = x;
    unsigned r = v.u + 0x7FFFu + ((v.u >> 16) & 1u);
    return (u16)(r >> 16);
}
DEV float bf2f(u16 h) { return __uint_as_float(((unsigned)h) << 16); }

#define SBAR() do { __builtin_amdgcn_sched_barrier(0); __builtin_amdgcn_s_barrier(); __builtin_amdgcn_sched_barrier(0); } while (0)
#define LGKM0() do { asm volatile("s_waitcnt lgkmcnt(0)" ::: "memory"); __builtin_amdgcn_sched_barrier(0); } while (0)

// ---------------- weight / input conversion ----------------
struct WPtrs { const float* p[16]; };

__global__ void k_conv_w(WPtrs wp, u16* wd, u16* wq) {
    int t = blockIdx.x * 256 + threadIdx.x;
    int mat = t >> 14;
    int e = (t & 16383) << 2;
    const float* s = wp.p[mat] + e;
    u16* d = (mat < 8 ? wd + mat * 65536 : wq + (mat - 8) * 65536) + e;
    float4 v = *(const float4*)s;
    d[0] = f2bf(v.x); d[1] = f2bf(v.y); d[2] = f2bf(v.z); d[3] = f2bf(v.w);
}

__global__ void k_conv_x(const float* dn, const float* qn, u16* xd, u16* xq) {
    int t = blockIdx.x * 256 + threadIdx.x;
    int h = t >> 19;
    int e = (t & 524287) << 2;
    const float* s = (h ? qn : dn) + e;
    u16* d = (h ? xq : xd) + e;
    float4 v = *(const float4*)s;
    d[0] = f2bf(v.x); d[1] = f2bf(v.y); d[2] = f2bf(v.z); d[3] = f2bf(v.w);
}

// ---------------- mask pre-pass: pack to bit-planes + nb rowsums ----------------
struct QuadCfg {
    const int* rm; const int* cm; int roff, coff, diag;
    unsigned* pl; unsigned* pr; unsigned char* dgp; float* nb;
};

__global__ __launch_bounds__(256) void k_mask(QuadCfg q0, QuadCfg q1, QuadCfg q2, QuadCfg q3,
        const int* ner, const int* graph) {
    const int z = blockIdx.z;
    const QuadCfg c = z == 0 ? q0 : z == 1 ? q1 : z == 2 ? q2 : q3;
    const int b = blockIdx.y;
    const int t = threadIdx.x;
    const int sub = t >> 5, w = t & 31;
    const int i = blockIdx.x * 8 + sub;
    const int rm = c.rm[b * 1024 + i] != 0;
    size_t rowbase = ((size_t)(b * 2048 + c.roff + i)) * 2048 + c.coff + w * 32;
    const int4* np = (const int4*)(ner + rowbase);
    const int4* gp = (const int4*)(graph + rowbase);
    const int4* cp = (const int4*)(c.cm + b * 1024 + w * 32);
    unsigned v = 0, gw = 0;
#pragma unroll
    for (int k = 0; k < 8; ++k) {
        int4 nv = np[k], gv = gp[k], cv = cp[k];
        unsigned bs = k * 4;
        v  |= ((unsigned)(rm & (cv.x != 0) & (nv.x != 0))) << bs;
        v  |= ((unsigned)(rm & (cv.y != 0) & (nv.y != 0))) << (bs + 1);
        v  |= ((unsigned)(rm & (cv.z != 0) & (nv.z != 0))) << (bs + 2);
        v  |= ((unsigned)(rm & (cv.w != 0) & (nv.w != 0))) << (bs + 3);
        gw |= ((unsigned)(gv.x != 0)) << bs;
        gw |= ((unsigned)(gv.y != 0)) << (bs + 1);
        gw |= ((unsigned)(gv.z != 0)) << (bs + 2);
        gw |= ((unsigned)(gv.w != 0)) << (bs + 3);
    }
    unsigned e = v;
    if (c.diag && (i >> 5) == w) {
        e &= ~(1u << (i & 31));
        c.dgp[b * 1024 + i] = (unsigned char)((v >> (i & 31)) & 1u);
    }
    unsigned lb = e & gw, rb = e & ~gw;
    size_t widx = ((size_t)(b * 1024 + i)) * 32 + w;
    c.pl[widx] = lb;
    c.pr[widx] = rb;
    int cnt = __popc(e);
    cnt += __shfl_xor(cnt, 1); cnt += __shfl_xor(cnt, 2);
    cnt += __shfl_xor(cnt, 4); cnt += __shfl_xor(cnt, 8); cnt += __shfl_xor(cnt, 16);
    if (w == 0) atomicAdd(c.nb + b * 1024 + i, (float)cnt);
}

// ---------------- projection GEMM: out = X @ W^T ----------------
__global__ __launch_bounds__(256, 1) void k_proj(const u16* xd, const u16* xq,
        const u16* wdm, const u16* wqm, u16* tokd, u16* tokq, u16* vtd, u16* vtq) {
    __shared__ __align__(16) char smem[16384];
    char* As = smem; char* Bs = smem + 8192;
    const int lane = threadIdx.x & 63, wid = threadIdx.x >> 6;
    const int z = blockIdx.z, grp = z >> 3, w = z & 7;
    const u16* X = grp ? xq : xd;
    const u16* W = (grp ? wqm : wdm) + w * 65536;
    const int m0 = blockIdx.x * 128, n0 = blockIdx.y * 128;
    const int wr = wid >> 1, wc = wid & 1;
    const int rl = lane & 15, g = lane >> 4;
    const f32x4 fz = {0.f, 0.f, 0.f, 0.f};
    f32x4 acc[4][4];
#pragma unroll
    for (int i = 0; i < 4; ++i)
#pragma unroll
        for (int j = 0; j < 4; ++j) acc[i][j] = fz;

    for (int kt = 0; kt < 8; ++kt) {
#pragma unroll
        for (int t = 0; t < 2; ++t) {
            int iid = wid * 2 + t;
            int ldso = iid * 1024 + lane * 16;
            int row = ldso >> 6, inrow = ldso & 63;
            int src = inrow ^ ((row & 3) << 4);
            gld16((const char*)X + ((size_t)(m0 + row) * 512 + kt * 64 + src), As + iid * 1024);
            gld16((const char*)W + ((size_t)(n0 + row) * 512 + kt * 64 + src), Bs + iid * 1024);
        }
        __syncthreads();
        s16x8 av[4], bv[4];
#pragma unroll
        for (int rf = 0; rf < 4; ++rf) {
            int row = wr * 64 + rf * 16 + rl;
            av[rf] = *(const s16x8*)(As + row * 64 + ((g * 16) ^ ((row & 3) << 4)));
        }
#pragma unroll
        for (int cf = 0; cf < 4; ++cf) {
            int row = wc * 64 + cf * 16 + rl;
            bv[cf] = *(const s16x8*)(Bs + row * 64 + ((g * 16) ^ ((row & 3) << 4)));
        }
#pragma unroll
        for (int rf = 0; rf < 4; ++rf)
#pragma unroll
            for (int cf = 0; cf < 4; ++cf)
                acc[rf][cf] = mfma16(av[rf], bv[cf], acc[rf][cf]);
        __syncthreads();
    }
    if (w < 4) {
        u16* out = (grp ? tokq : tokd) + (size_t)w * 2097152;
#pragma unroll
        for (int rf = 0; rf < 4; ++rf)
#pragma unroll
            for (int cf = 0; cf < 4; ++cf) {
                int n = n0 + wc * 64 + cf * 16 + rl;
                int m = m0 + wr * 64 + rf * 16 + g * 4;
#pragma unroll
                for (int r = 0; r < 4; ++r)
                    out[(size_t)(m + r) * 256 + n] = f2bf(acc[rf][cf][r]);
            }
    } else {
        u16* out = (grp ? vtq : vtd) + (size_t)(w - 4) * 2097152;
#pragma unroll
        for (int rf = 0; rf < 4; ++rf)
#pragma unroll
            for (int cf = 0; cf < 4; ++cf) {
                int n = n0 + wc * 64 + cf * 16 + rl;
                int m = m0 + wr * 64 + rf * 16 + g * 4;
                int b = m >> 10, tok = m & 1023;
                unsigned lo = (unsigned)f2bf(acc[rf][cf][0]) | ((unsigned)f2bf(acc[rf][cf][1]) << 16);
                unsigned hi = (unsigned)f2bf(acc[rf][cf][2]) | ((unsigned)f2bf(acc[rf][cf][3]) << 16);
                uint2 u; u.x = lo; u.y = hi;
                *(uint2*)(out + ((size_t)(b * 256 + n)) * 1024 + tok) = u;
            }
    }
}

// ---------------- fused masked attention (one quadrant per z) ----------------
struct PhaseCfg {
    const u16* Q; const u16* K; const u16* Vl; const u16* Vr;
    const unsigned* pl; const unsigned* pr; const unsigned char* dgp;
    float scale; float* po;
};

// BM=32, TILE_J=32, 2 waves x (16 full rows x 32 cols). Full-row softmax
// in-wave -> NO cross-wave max exchange -> 2 barriers/iter:
//   (A) K-ready [vmcnt(16) drains stage issued last iter]
//   (B) P-ready [lgkm]
// Load order: vl/vr at top (before A); STAGE_K(next)+MLOAD(next) after B
// -> PV's auto-waitcnt is vmcnt(16): never waits on the in-flight stage.
// Fused L/R accumulator: acc = mfma(pb,vr, mfma(pa,vl,acc)) (sum is linear).
// LDS 21760B: Ks@0 16K, Pl@16384 2560, Pr@18944 2560, rsS@21504 128, dpS@21632 128
__global__ __launch_bounds__(128, 2) void k_attn(PhaseCfg c0, PhaseCfg c1,
        PhaseCfg c2, PhaseCfg c3) {
    // bijective XCD swizzle: groups each (b,z)'s 32 i-blocks on one XCD
    const int lin = blockIdx.x + 32 * blockIdx.y + 256 * blockIdx.z;
    const int xcd = lin & 7, kk0 = lin >> 3;
    const int p = xcd * 4 + (kk0 >> 5);
    const int i0 = (kk0 & 31) * 32;
    const int z = p >> 3, b = p & 7;
    const PhaseCfg c = z == 0 ? c0 : z == 1 ? c1 : z == 2 ? c2 : c3;
    const int lane = threadIdx.x & 63, w = threadIdx.x >> 6;   // 2 waves
    const int rl = lane & 15, g = lane >> 4;

    __shared__ __align__(16) char smem[21760];
    u16* Pls = (u16*)(smem + 16384);
    u16* Prs = (u16*)(smem + 18944);
    float* rsS = (float*)(smem + 21504);
    float* dpS = (float*)(smem + 21632);

    const char* Kg  = (const char*)c.K  + (size_t)b * 524288;
    const char* Vlg = (const char*)c.Vl + (size_t)b * 524288;
    const char* Vrg = (const char*)c.Vr + (size_t)b * 524288;

    // Q fragments in regs: rows i0 + w*16 + rl, k = kf*32 + g*8
    s16x8 qf[8];
    {
        const u16* Qb = c.Q + (size_t)(b * 1024 + i0 + w * 16 + rl) * 256 + g * 8;
#pragma unroll
        for (int kf = 0; kf < 8; ++kf) qf[kf] = *(const s16x8*)(Qb + kf * 32);
    }
    const int iqb = i0 + w * 16 + g * 4;
    const unsigned* lpRow = c.pl + ((size_t)(b << 10) + iqb) * 32;
    const unsigned* rpRow = c.pr + ((size_t)(b << 10) + iqb) * 32;

    unsigned dgv[4];
#pragma unroll
    for (int r = 0; r < 4; ++r)
        dgv[r] = c.dgp ? (unsigned)c.dgp[b * 1024 + iqb + r] : 0u;

    // stage K tile: 16KB, 8 gld16 per wave (128 threads)
    auto STAGE_K = [&](int j0) {
#pragma unroll
        for (int t = 0; t < 8; ++t) {
            int iid = t * 2 + w;
            int ldso = iid * 1024 + lane * 16;
            int row = ldso >> 9, inrow = ldso & 511;
            int src = inrow ^ ((row & 7) << 4);
            gld16(Kg + ((size_t)(j0 + row) * 512 + src), smem + iid * 1024);
        }
    };
    // masks for current tile, prefetched one iteration ahead (8 regs)
    unsigned lw[4], rw[4];
    auto MLOAD = [&](int jt) {
#pragma unroll
        for (int r = 0; r < 4; ++r) {
            lw[r] = lpRow[r * 32 + jt];
            rw[r] = rpRow[r * 32 + jt];
        }
    };

    STAGE_K(0);
    MLOAD(0);

    const f32x4 fz = {0.f, 0.f, 0.f, 0.f};
    f32x4 acc[2][8];
#pragma unroll
    for (int i = 0; i < 2; ++i)
#pragma unroll
        for (int j = 0; j < 8; ++j) acc[i][j] = fz;
    float mrow[4] = {-1e30f, -1e30f, -1e30f, -1e30f};
    float dden[4] = {0.f, 0.f, 0.f, 0.f};

#pragma unroll 1
    for (int jt = 0; jt < 32; ++jt) {
        const int j0 = jt * 32;

        // V fragments for wave's 128-ch slice (channel-major, 16B coalesced)
        s16x8 vl[8], vr[8];
#pragma unroll
        for (int cf = 0; cf < 8; ++cf) {
            size_t off = (size_t)(w * 128 + cf * 16 + rl) * 2048 + (size_t)(j0 + g * 8) * 2;
            vl[cf] = *(const s16x8*)(Vlg + off);
            vr[cf] = *(const s16x8*)(Vrg + off);
        }
        // in-flight: STAGE_K(jt)=8 + MLOAD(jt)=8 (issued last iter), vl/vr=16
        // drain stage+masks, keep vl/vr flying
        asm volatile("s_waitcnt vmcnt(16)" ::: "memory");
        SBAR();   // (A) K tile visible

        // S = Q K^T : 16 rows x 32 cols, all in-wave
        f32x4 s0 = fz, s1 = fz;
#pragma unroll
        for (int kk = 0; kk < 8; ++kk) {
            int jr0 = rl, jr1 = 16 + rl;
            s16x8 b0 = *(const s16x8*)(smem + jr0 * 512 + ((kk * 64 + g * 16) ^ ((jr0 & 7) << 4)));
            s16x8 b1 = *(const s16x8*)(smem + jr1 * 512 + ((kk * 64 + g * 16) ^ ((jr1 & 7) << 4)));
            s0 = mfma16(qf[kk], b0, s0);
            s1 = mfma16(qf[kk], b1, s1);
        }

        // masks from bits; cols rl (bit rl) and 16+rl (bit 16+rl)
        float sv0[4], sv1[4];
        int l0[4], l1[4], r0m[4], r1m[4];
#pragma unroll
        for (int r = 0; r < 4; ++r) {
            unsigned vw = lw[r] | rw[r];
            int row = iqb + r;
            if (jt == (row >> 5)) vw |= dgv[r] << (row & 31);
            int v0 = (vw >> rl) & 1;
            int v1 = (vw >> (16 + rl)) & 1;
            sv0[r] = v0 ? s0[r] * c.scale : -1e30f;
            sv1[r] = v1 ? s1[r] * c.scale : -1e30f;
            l0[r] = (lw[r] >> rl) & 1;        r0m[r] = (rw[r] >> rl) & 1;
            l1[r] = (lw[r] >> (16 + rl)) & 1; r1m[r] = (rw[r] >> (16 + rl)) & 1;
        }
        // full-row max in-wave (over 32 cols)
        float rsv[4];
#pragma unroll
        for (int r = 0; r < 4; ++r) {
            float t = fmaxf(sv0[r], sv1[r]);
            t = fmaxf(t, __shfl_xor(t, 1));
            t = fmaxf(t, __shfl_xor(t, 2));
            t = fmaxf(t, __shfl_xor(t, 4));
            t = fmaxf(t, __shfl_xor(t, 8));
            float mn = fmaxf(mrow[r], t);
            rsv[r] = __expf(mrow[r] - mn);
            mrow[r] = mn;
            float e0 = __expf(sv0[r] - mn);
            float e1 = __expf(sv1[r] - mn);
            dden[r] = dden[r] * rsv[r] + e0 + e1;
            int prow = w * 16 + g * 4 + r;
            Pls[prow * 40 + rl]      = l0[r]  ? f2bf(e0) : (u16)0;
            Pls[prow * 40 + 16 + rl] = l1[r]  ? f2bf(e1) : (u16)0;
            Prs[prow * 40 + rl]      = r0m[r] ? f2bf(e0) : (u16)0;
            Prs[prow * 40 + 16 + rl] = r1m[r] ? f2bf(e1) : (u16)0;
        }
        if (rl == 0) {
            f32x4 rv = {rsv[0], rsv[1], rsv[2], rsv[3]};
            *(f32x4*)(rsS + w * 16 + g * 4) = rv;
        }
        LGKM0();
        SBAR();   // (B) P + rescale visible; K reads done -> stage WAR safe

        if (jt < 31) { STAGE_K(j0 + 32); MLOAD(jt + 1); }

        // PV: wave's 128-ch slice over all 32 rows; vl/vr already in regs
        f32x4 rs4[2];
#pragma unroll
        for (int rf = 0; rf < 2; ++rf) rs4[rf] = *(const f32x4*)(rsS + rf * 16 + g * 4);
#pragma unroll
        for (int rf = 0; rf < 2; ++rf)
#pragma unroll
            for (int cf = 0; cf < 8; ++cf) acc[rf][cf] *= rs4[rf];
        s16x8 pa[2], pb[2];
#pragma unroll
        for (int rf = 0; rf < 2; ++rf) {
            pa[rf] = *(const s16x8*)((char*)Pls + (rf * 16 + rl) * 80 + g * 16);
            pb[rf] = *(const s16x8*)((char*)Prs + (rf * 16 + rl) * 80 + g * 16);
        }
#pragma unroll
        for (int rf = 0; rf < 2; ++rf)
#pragma unroll
            for (int cf = 0; cf < 8; ++cf)
                acc[rf][cf] = mfma16(pb[rf], vr[cf], mfma16(pa[rf], vl[cf], acc[rf][cf]));
    }

    // denominators: reduce over rl, exchange across the 2 waves
#pragma unroll
    for (int r = 0; r < 4; ++r) {
        float d = dden[r];
        d += __shfl_xor(d, 1); d += __shfl_xor(d, 2); d += __shfl_xor(d, 4); d += __shfl_xor(d, 8);
        dden[r] = d;
    }
    if (rl == 0) {
        f32x4 dv = {dden[0], dden[1], dden[2], dden[3]};
        *(f32x4*)(dpS + w * 16 + g * 4) = dv;
    }
    __syncthreads();

#pragma unroll
    for (int rf = 0; rf < 2; ++rf) {
        f32x4 dt = *(const f32x4*)(dpS + rf * 16 + g * 4);
#pragma unroll
        for (int cf = 0; cf < 8; ++cf) {
            int col = w * 128 + cf * 16 + rl;
#pragma unroll
            for (int r = 0; r < 4; ++r) {
                int row = i0 + rf * 16 + g * 4 + r;
                size_t oi = (size_t)(b * 1024 + row) * 256 + col;
                float inv = dt[r] > 0.f ? 1.f / dt[r] : 0.f;
                c.po[oi] = acc[rf][cf][r] * inv;
            }
        }
    }
}

// ---------------- combine: out = relu(self + bias + (pA+pB)/max(nb,1)) ----------------
struct FinCfg {
    const float* pA; const float* pB; const float* nb;
    const u16* self; float* out;
};

__global__ __launch_bounds__(256) void k_fin(FinCfg f0, FinCfg f1, const float* bias) {
    const FinCfg f = blockIdx.y ? f1 : f0;
    int row = blockIdx.x * 4 + (threadIdx.x >> 6);
    int ch = (threadIdx.x & 63) * 4;
    size_t oi = (size_t)row * 256 + ch;
    float inv = 1.f / fmaxf(f.nb[row], 1.f);
    f32x4 a = *(const f32x4*)(f.pA + oi);
    f32x4 p = *(const f32x4*)(f.pB + oi);
    f32x4 bi = *(const f32x4*)(bias + ch);
    uint2 sv = *(const uint2*)(f.self + oi);
    float s[4] = { bf2f((u16)(sv.x & 0xffff)), bf2f((u16)(sv.x >> 16)),
                   bf2f((u16)(sv.y & 0xffff)), bf2f((u16)(sv.y >> 16)) };
    f32x4 o;
#pragma unroll
    for (int k = 0; k < 4; ++k)
        o[k] = fmaxf(s[k] + bi[k] + (a[k] + p[k]) * inv, 0.f);
    *(f32x4*)(f.out + oi) = o;
}

// ---------------- host ----------------
extern "C" void kernel_launch(void* const* d_in, const int* in_sizes, int n_in,
                              void* d_out, int out_size, void* d_ws, size_t ws_size,
                              hipStream_t stream) {
    (void)in_sizes; (void)n_in; (void)out_size; (void)ws_size;
    const float* d_node = (const float*)d_in[0];
    const float* q_node = (const float*)d_in[1];
    const float* b_self = (const float*)d_in[9];
    const int* dm = (const int*)d_in[18];
    const int* qm = (const int*)d_in[19];
    const int* ner = (const int*)d_in[20];
    const int* graph = (const int*)d_in[21];

    char* ws = (char*)d_ws;
    const size_t MB = 1024 * 1024;
    u16* xd   = (u16*)(ws + 0 * MB);
    u16* xq   = (u16*)(ws + 4 * MB);
    u16* wdm  = (u16*)(ws + 8 * MB);
    u16* wqm  = (u16*)(ws + 9 * MB);
    u16* tokd = (u16*)(ws + 10 * MB);     // [Qd, Kd, Kqd, SelfD]
    u16* tokq = (u16*)(ws + 26 * MB);     // [Qq, Kq, Kdq, SelfQ]
    u16* vtd  = (u16*)(ws + 42 * MB);     // [ddl, ddr, qdl, qdr] channel-major
    u16* vtq  = (u16*)(ws + 58 * MB);     // [qql, qqr, dql, dqr]
    float* nb_d = (float*)(ws + 74 * MB);
    float* nb_q = (float*)(ws + 74 * MB + 32768);
    unsigned char* dgd = (unsigned char*)(ws + 74 * MB + 65536);
    unsigned char* dgq = (unsigned char*)(ws + 74 * MB + 73728);
    float* Pdq  = (float*)(ws + 75 * MB);
    float* Pqd  = (float*)(ws + 83 * MB);
    unsigned* pl_dd = (unsigned*)(ws + 91 * MB);
    unsigned* pl_qq = (unsigned*)(ws + 92 * MB);
    unsigned* pl_dq = (unsigned*)(ws + 93 * MB);
    unsigned* pl_qd = (unsigned*)(ws + 94 * MB);
    unsigned* pr_dd = (unsigned*)(ws + 95 * MB);
    unsigned* pr_qq = (unsigned*)(ws + 96 * MB);
    unsigned* pr_dq = (unsigned*)(ws + 97 * MB);
    unsigned* pr_qd = (unsigned*)(ws + 98 * MB);

    float* outd = (float*)d_out;
    float* outq = outd + 2097152;

    WPtrs wp;
    wp.p[0]  = (const float*)d_in[2];   // W_dq_query -> Qd
    wp.p[1]  = (const float*)d_in[3];   // W_dk_key   -> Kd
    wp.p[2]  = (const float*)d_in[7];   // W_qd_fc    -> Kqd
    wp.p[3]  = (const float*)d_in[8];   // W_self     -> SelfD
    wp.p[4]  = (const float*)d_in[10];  // W_dd_l
    wp.p[5]  = (const float*)d_in[14];  // W_dd_r
    wp.p[6]  = (const float*)d_in[13];  // W_qd_l
    wp.p[7]  = (const float*)d_in[17];  // W_qd_r
    wp.p[8]  = (const float*)d_in[4];   // W_qq_query -> Qq
    wp.p[9]  = (const float*)d_in[5];   // W_qk_key   -> Kq
    wp.p[10] = (const float*)d_in[6];   // W_dq_fc    -> Kdq
    wp.p[11] = (const float*)d_in[8];   // W_self     -> SelfQ
    wp.p[12] = (const float*)d_in[11];  // W_qq_l
    wp.p[13] = (const float*)d_in[15];  // W_qq_r
    wp.p[14] = (const float*)d_in[12];  // W_dq_l
    wp.p[15] = (const float*)d_in[16];  // W_dq_r

    (void)hipMemsetAsync(ws + 74 * MB, 0, 65536, stream);   // nb_d + nb_q

    k_conv_w<<<1024, 256, 0, stream>>>(wp, wdm, wqm);
    k_conv_x<<<4096, 256, 0, stream>>>(d_node, q_node, xd, xq);

    QuadCfg mdd = { dm, dm, 0, 0, 1, pl_dd, pr_dd, dgd, nb_d };
    QuadCfg mqq = { qm, qm, 1024, 1024, 1, pl_qq, pr_qq, dgq, nb_q };
    QuadCfg mdq = { dm, qm, 0, 1024, 0, pl_dq, pr_dq, nullptr, nb_d };
    QuadCfg mqd = { qm, dm, 1024, 0, 0, pl_qd, pr_qd, nullptr, nb_q };
    k_mask<<<dim3(128, 8, 4), 256, 0, stream>>>(mdd, mqq, mdq, mqd, ner, graph);

    k_proj<<<dim3(64, 2, 16), 256, 0, stream>>>(xd, xq, wdm, wqm, tokd, tokq, vtd, vtq);

    const size_t M2 = 2097152;
    PhaseCfg dd = { tokd,          tokd + M2,     vtd,          vtd + M2,
                    pl_dd, pr_dd, dgd, 0.0625f, outd };
    PhaseCfg qq = { tokq,          tokq + M2,     vtq,          vtq + M2,
                    pl_qq, pr_qq, dgq, 0.0625f, outq };
    PhaseCfg dq = { xd,            tokq + 2 * M2, vtq + 2 * M2, vtq + 3 * M2,
                    pl_dq, pr_dq, nullptr, 1.0f, Pdq };
    PhaseCfg qd = { xq,            tokd + 2 * M2, vtd + 2 * M2, vtd + 3 * M2,
                    pl_qd, pr_qd, nullptr, 1.0f, Pqd };
    k_attn<<<dim3(32, 8, 4), 128, 0, stream>>>(dd, qq, dq, qd);

    FinCfg fd = { outd, Pdq, nb_d, tokd + 3 * M2, outd };
    FinCfg fq = { outq, Pqd, nb_q, tokq + 3 * M2, outq };
    k_fin<<<dim3(2048, 2), 256, 0, stream>>>(fd, fq, b_self);
}